// Round 18
// baseline (842.542 us; speedup 1.0000x reference)
//
#include <hip/hip_runtime.h>
#include <hip/hip_bf16.h>
#include <cstdint>
#include <cstddef>

typedef __bf16 bf16;
typedef __bf16 bf16x8 __attribute__((ext_vector_type(8)));
typedef __bf16 bf16x4 __attribute__((ext_vector_type(4)));
typedef float f32x4 __attribute__((ext_vector_type(4)));

#define MFMA16(a, b, c) __builtin_amdgcn_mfma_f32_16x16x32_bf16((a), (b), (c), 0, 0, 0)
#define GLL16(gp, lp) __builtin_amdgcn_global_load_lds( \
    (const __attribute__((address_space(1))) void*)(gp), \
    (__attribute__((address_space(3))) void*)(lp), 16, 0, 0)

#define LDS_FENCE() do { \
    __builtin_amdgcn_sched_barrier(0); \
    asm volatile("s_waitcnt lgkmcnt(0)" ::: "memory"); \
    __builtin_amdgcn_sched_barrier(0); \
  } while (0)

__device__ __forceinline__ bf16x8 cvt8(const float* f) {
  bf16x8 h;
  #pragma unroll
  for (int j = 0; j < 8; ++j) h[j] = (bf16)f[j];
  return h;
}

__device__ __forceinline__ bf16x8 ldb8(const bf16* p) {
  return *(const bf16x8*)p;
}
__device__ __forceinline__ bf16x8 ldb8(const float* p) {
  float f[8];
  *(f32x4*)&f[0] = *(const f32x4*)p;
  *(f32x4*)&f[4] = *(const f32x4*)(p + 4);
  return cvt8(f);
}

__global__ void write_val(float* o, float v) {
  if (threadIdx.x == 0 && blockIdx.x == 0) o[0] = v;
}

// ---------------------------------------------------------------------------
// fp32 -> bf16 conversion pass. n8 = elems/8.
// ---------------------------------------------------------------------------
__global__ __launch_bounds__(256) void cvt_pass(
    const float* __restrict__ src, bf16* __restrict__ dst, size_t n8)
{
  for (size_t i = (size_t)blockIdx.x * 256 + threadIdx.x; i < n8;
       i += (size_t)gridDim.x * 256) {
    float f[8];
    *(f32x4*)&f[0] = *(const f32x4*)&src[i * 8];
    *(f32x4*)&f[4] = *(const f32x4*)&src[i * 8 + 4];
    *(bf16x8*)&dst[i * 8] = cvt8(f);
  }
}

// ---------------------------------------------------------------------------
// Pipelined 256x256 bf16 GEMM, THREE B/C regions. BK=32, 4 LDS buffers,
// counted vmcnt(8), 8 waves, GLL16 staging.
// R18: (a) bank-swizzle key fixed for 64B rows: (row>>1)&3 (was row&3 ->
//      4-way conflict for q=0,4,8,12); (b) bijective XCD-chunked block remap.
// Numerics identical to R15/R16/R17 (same k-accumulation chain).
// ---------------------------------------------------------------------------
template <typename CT>
__global__ __launch_bounds__(512, 2) void gemm256_3(
    const bf16* __restrict__ A,
    const bf16* __restrict__ B0, const bf16* __restrict__ B1,
    const bf16* __restrict__ B2, int n1, int n2,
    CT* __restrict__ C0, CT* __restrict__ C1, CT* __restrict__ C2,
    int K, size_t aBatch, size_t cb0, size_t cb1, size_t cb2,
    int ld0, int ld1, int ld2)
{
  __shared__ bf16 lds[4 * 16384];
  const int tid  = threadIdx.x;
  const int wave = tid >> 6, lane = tid & 63;
  const int g = lane >> 4, q = lane & 15;
  const int wm = wave >> 2, wn = wave & 3;

  // XCD-aware bijective block remap (all grids here have nwg % 8 == 0)
  const int gx = gridDim.x, gy = gridDim.y;
  const int nwg = gx * gy * gridDim.z;
  int fid = blockIdx.x + gx * (blockIdx.y + gy * blockIdx.z);
  const int cpx = nwg >> 3;
  fid = (fid & 7) * cpx + (fid >> 3);
  const int bx = fid % gx;
  const int rem = fid / gx;
  const int by = rem % gy;
  const int bz = rem / gy;

  const int r = (bx < n1) ? 0 : (bx < n2) ? 1 : 2;
  const bf16* Bw = (r == 0) ? B0 : (r == 1) ? B1 : B2;
  CT* C = ((r == 0) ? C0 : (r == 1) ? C1 : C2)
          + (size_t)bz * ((r == 0) ? cb0 : (r == 1) ? cb1 : cb2);
  const int bn = bx - ((r == 0) ? 0 : (r == 1) ? n1 : n2);
  const int ldc = (r == 0) ? ld0 : (r == 1) ? ld1 : ld2;
  const size_t n0 = (size_t)bn * 256;
  const size_t m0 = (size_t)by * 256;
  const bf16* Ap = A + (size_t)bz * aBatch;

  // staging: dest linear granule tid -> row = i*128 + (tid>>2), slot = tid&3;
  // source slot pre-swizzled by key = (row>>1)&3 = (tid>>3)&3.
  const int srow = tid >> 2;
  const int scol = (((tid & 3) ^ ((tid >> 3) & 3)) << 3);
  const int NT = K >> 5;

  f32x4 acc[8][4] = {};

  auto STAGE_A = [&](int t) {
    const int k0 = t << 5;
    char* base = (char*)lds + (size_t)(t & 3) * 32768 + wave * 1024;
    #pragma unroll
    for (int i = 0; i < 2; ++i)
      GLL16(&Ap[(m0 + i * 128 + srow) * (size_t)K + k0 + scol],
            base + i * 8192);
  };
  auto STAGE_B = [&](int t) {
    const int k0 = t << 5;
    char* base = (char*)lds + (size_t)(t & 3) * 32768 + 16384 + wave * 1024;
    #pragma unroll
    for (int i = 0; i < 2; ++i)
      GLL16(&Bw[(n0 + i * 128 + srow) * (size_t)K + k0 + scol],
            base + i * 8192);
  };

  STAGE_A(0); STAGE_B(0);
  STAGE_A(1); STAGE_B(1);
  STAGE_A(2); STAGE_B(2);

  const int rsl = ((g ^ ((q >> 1) & 3)) << 3);   // read slot, key (row>>1)&3

  for (int t = 0; t < NT; ++t) {
    asm volatile("s_waitcnt vmcnt(8)" ::: "memory");
    __builtin_amdgcn_sched_barrier(0);
    __builtin_amdgcn_s_barrier();
    const bf16* lA = lds + (size_t)(t & 3) * 16384;
    const bf16* lB = lA + 8192;

    bf16x8 bfr[4], af[4];
    #pragma unroll
    for (int fn = 0; fn < 4; ++fn)
      bfr[fn] = *(const bf16x8*)&lB[(wn * 64 + fn * 16 + q) * 32 + rsl];
    #pragma unroll
    for (int fm = 0; fm < 4; ++fm)
      af[fm] = *(const bf16x8*)&lA[(wm * 128 + fm * 16 + q) * 32 + rsl];
    if (t + 3 < NT) STAGE_A(t + 3);
    asm volatile("s_waitcnt lgkmcnt(0)" ::: "memory");
    __builtin_amdgcn_sched_barrier(0);
    __builtin_amdgcn_s_setprio(1);
    #pragma unroll
    for (int fm = 0; fm < 4; ++fm)
      #pragma unroll
      for (int fn = 0; fn < 4; ++fn)
        acc[fm][fn] = MFMA16(af[fm], bfr[fn], acc[fm][fn]);
    __builtin_amdgcn_s_setprio(0);
    __builtin_amdgcn_s_barrier();

    #pragma unroll
    for (int fm = 0; fm < 4; ++fm)
      af[fm] = *(const bf16x8*)&lA[(wm * 128 + (fm + 4) * 16 + q) * 32 + rsl];
    if (t + 3 < NT) STAGE_B(t + 3);
    asm volatile("s_waitcnt lgkmcnt(0)" ::: "memory");
    __builtin_amdgcn_sched_barrier(0);
    __builtin_amdgcn_s_setprio(1);
    #pragma unroll
    for (int fm = 0; fm < 4; ++fm)
      #pragma unroll
      for (int fn = 0; fn < 4; ++fn)
        acc[fm + 4][fn] = MFMA16(af[fm], bfr[fn], acc[fm + 4][fn]);
    __builtin_amdgcn_s_setprio(0);
  }

  #pragma unroll
  for (int fm = 0; fm < 8; ++fm)
    #pragma unroll
    for (int fn = 0; fn < 4; ++fn)
      #pragma unroll
      for (int rr = 0; rr < 4; ++rr) {
        const size_t row = m0 + wm * 128 + fm * 16 + g * 4 + rr;
        C[row * (size_t)ldc + n0 + wn * 64 + fn * 16 + q] = (CT)acc[fm][fn][rr];
      }
}

// ---------------------------------------------------------------------------
// 128^2 reg-staged GEMM (fp32-B fallback tier only).
// ---------------------------------------------------------------------------
template <typename CT, typename BT>
__global__ __launch_bounds__(256) void gemm_bf(
    const bf16* __restrict__ A,
    const BT* __restrict__ B0, const BT* __restrict__ B1, int nsplit,
    CT* __restrict__ C0, CT* __restrict__ C1,
    int K, size_t aBatch, size_t cBatch)
{
  constexpr int LDST = 72;
  __shared__ bf16 lA[128 * LDST];
  __shared__ bf16 lB[128 * LDST];
  const int tid  = threadIdx.x;
  const int wave = tid >> 6;
  const int lane = tid & 63;
  const int g = lane >> 4, q = lane & 15;
  const bool r0 = (int)blockIdx.x < nsplit;
  const BT* Bw = r0 ? B0 : B1;
  CT* C = (r0 ? C0 : C1) + blockIdx.z * cBatch;
  const int bn = r0 ? blockIdx.x : blockIdx.x - nsplit;
  const int ldc = (r0 ? nsplit : ((int)gridDim.x - nsplit)) * 128;
  const size_t n0 = (size_t)bn * 128;
  const size_t m0 = (size_t)blockIdx.y * 128;
  const bf16* Ap = A + blockIdx.z * aBatch;
  const int wm = wave >> 1, wn = wave & 1;
  const int sr = tid >> 3, sc8 = (tid & 7) << 3;

  f32x4 acc[4][4] = {};

  for (int k0 = 0; k0 < K; k0 += 64) {
    __syncthreads();
    #pragma unroll
    for (int i = 0; i < 4; ++i) {
      const int row = i * 32 + sr;
      *(bf16x8*)&lA[row * LDST + sc8] = ldb8(&Ap[(m0 + row) * (size_t)K + k0 + sc8]);
      *(bf16x8*)&lB[row * LDST + sc8] = ldb8(&Bw[(n0 + row) * (size_t)K + k0 + sc8]);
    }
    __syncthreads();
    #pragma unroll
    for (int kk = 0; kk < 2; ++kk) {
      bf16x8 af[4], bfr[4];
      #pragma unroll
      for (int f = 0; f < 4; ++f) {
        af[f]  = *(const bf16x8*)&lA[(wm * 64 + f * 16 + q) * LDST + kk * 32 + g * 8];
        bfr[f] = *(const bf16x8*)&lB[(wn * 64 + f * 16 + q) * LDST + kk * 32 + g * 8];
      }
      #pragma unroll
      for (int fm = 0; fm < 4; ++fm)
        #pragma unroll
        for (int fn = 0; fn < 4; ++fn)
          acc[fm][fn] = MFMA16(af[fm], bfr[fn], acc[fm][fn]);
    }
  }

  #pragma unroll
  for (int fm = 0; fm < 4; ++fm)
    #pragma unroll
    for (int fn = 0; fn < 4; ++fn)
      #pragma unroll
      for (int r = 0; r < 4; ++r) {
        const size_t row = m0 + wm * 64 + fm * 16 + g * 4 + r;
        C[row * (size_t)ldc + n0 + wn * 64 + fn * 16 + q] = (CT)acc[fm][fn][r];
      }
}

// ---------------------------------------------------------------------------
// Gemma RMSNorm + RoPE, wave per (row, head): 64 lanes x 4 elems, in place.
// ---------------------------------------------------------------------------
__global__ __launch_bounds__(256) void norm_rope_w(
    bf16* __restrict__ data, const float* __restrict__ w,
    const float* __restrict__ ropec, int lnh, int hstride, int rowlen,
    int s_off)
{
  const int lane = threadIdx.x & 63;
  const int wid  = blockIdx.x * 4 + (threadIdx.x >> 6);
  const int m = wid >> lnh;
  const int h = wid & ((1 << lnh) - 1);
  const int s = (s_off + m) & 2047;

  bf16* p = data + (size_t)m * rowlen + h * hstride + lane * 4;
  const bf16x4 xv = *(const bf16x4*)p;
  float x0 = (float)xv[0], x1 = (float)xv[1], x2 = (float)xv[2], x3 = (float)xv[3];
  float ss = x0*x0 + x1*x1 + x2*x2 + x3*x3;
  #pragma unroll
  for (int d = 1; d < 64; d <<= 1) ss += __shfl_xor(ss, d, 64);
  const float rr = rsqrtf(ss * (1.0f / 256.0f) + 1e-6f);
  const f32x4 wv4 = *(const f32x4*)&w[lane * 4];
  x0 *= rr * (1.0f + wv4[0]);
  x1 *= rr * (1.0f + wv4[1]);
  x2 *= rr * (1.0f + wv4[2]);
  x3 *= rr * (1.0f + wv4[3]);

  const float o0 = __shfl_xor(x0, 8, 64);
  const float o1 = __shfl_xor(x1, 8, 64);
  const float o2 = __shfl_xor(x2, 8, 64);
  const float o3 = __shfl_xor(x3, 8, 64);
  if (lane < 16) {
    const int c0 = lane * 4;
    const float* rc = ropec + (size_t)s * 128;
    const float sgn = (lane < 8) ? -1.0f : 1.0f;
    x0 = x0 * rc[c0]     + sgn * o0 * rc[64 + c0];
    x1 = x1 * rc[c0 + 1] + sgn * o1 * rc[64 + c0 + 1];
    x2 = x2 * rc[c0 + 2] + sgn * o2 * rc[64 + c0 + 2];
    x3 = x3 * rc[c0 + 3] + sgn * o3 * rc[64 + c0 + 3];
  }
  bf16x4 ov; ov[0] = (bf16)x0; ov[1] = (bf16)x1; ov[2] = (bf16)x2; ov[3] = (bf16)x3;
  *(bf16x4*)p = ov;
}

// ---------------------------------------------------------------------------
// bf16 MFMA flash attention v3 (R17-verified): double-buffered K (GLL) and
// V^T; per-tile prefetch; defer-max; setprio. 4 waves x 16 Q.
// ---------------------------------------------------------------------------
__global__ __launch_bounds__(256) void attn_b3(
    const bf16* __restrict__ qg, const bf16* __restrict__ kb,
    const bf16* __restrict__ vb, bf16* __restrict__ yb,
    size_t qgBatch, size_t kvBatch, size_t yBatch)
{
  __shared__ bf16 lK[2][32 * 256];
  __shared__ bf16 lVt[2][256 * 40];
  __shared__ bf16 lP[4 * 16 * 40];
  const int tid  = threadIdx.x;
  const int wave = tid >> 6, lane = tid & 63;
  const int g = lane >> 4, qc = lane & 15;
  const int h = blockIdx.y, q0 = blockIdx.x * 64, kvh = h >> 2;
  const int z = blockIdx.z;
  const bf16* qgp = qg + z * qgBatch;
  const bf16* kbase = kb + z * kvBatch + kvh * 256;
  const bf16* vbase = vb + z * kvBatch + kvh * 256;
  const int qrow = q0 + wave * 16 + qc;

  bf16x8 qf[8];
  {
    const bf16* qp = qgp + (size_t)qrow * 8192 + h * 512;
    #pragma unroll
    for (int kq = 0; kq < 8; ++kq)
      qf[kq] = *(const bf16x8*)&qp[kq * 32 + g * 8];
  }

  f32x4 o[16] = {};
  float mrow = -1e30f, lrow = 0.0f;
  const float scale = 0.0625f;
  const float L2E = 1.44269504f;
  const int vp = (tid & 15) * 2, vc = (tid >> 4) * 16;
  bf16* const pl = lP + wave * (16 * 40);
  const int krw = wave * 2 + (lane >> 5);
  const int ksl = lane & 31;

  auto stageK = [&](int tile, int buf) {
    const int t0 = tile * 32;
    #pragma unroll
    for (int i = 0; i < 4; ++i) {
      const int row = i * 8 + krw;
      GLL16(&kbase[(size_t)(t0 + row) * 1024 + ((ksl ^ (row & 7)) << 3)],
            (char*)lK[buf] + i * 4096 + wave * 1024);
    }
  };
  auto loadV = [&](int tile, bf16x8& a0, bf16x8& b0, bf16x8& a1, bf16x8& b1) {
    const bf16* p0 = vbase + (size_t)(tile * 32 + vp) * 1024 + vc;
    a0 = *(const bf16x8*)(p0);
    b0 = *(const bf16x8*)(p0 + 8);
    a1 = *(const bf16x8*)(p0 + 1024);
    b1 = *(const bf16x8*)(p0 + 1032);
  };
  auto writeVt = [&](int buf, const bf16x8& a0, const bf16x8& b0,
                     const bf16x8& a1, const bf16x8& b1) {
    unsigned* dst = (unsigned*)lVt[buf];
    #pragma unroll
    for (int j = 0; j < 8; ++j) {
      const int o0 = (vc + j) * 20 + (vp >> 1);
      const int o1 = (vc + 8 + j) * 20 + (vp >> 1);
      dst[o0] = (unsigned)__builtin_bit_cast(unsigned short, (bf16)a0[j]) |
                ((unsigned)__builtin_bit_cast(unsigned short, (bf16)a1[j]) << 16);
      dst[o1] = (unsigned)__builtin_bit_cast(unsigned short, (bf16)b0[j]) |
                ((unsigned)__builtin_bit_cast(unsigned short, (bf16)b1[j]) << 16);
    }
  };

  {
    bf16x8 a0, b0, a1, b1;
    stageK(0, 0);
    loadV(0, a0, b0, a1, b1);
    asm volatile("s_waitcnt vmcnt(0)" ::: "memory");
    __builtin_amdgcn_sched_barrier(0);
    writeVt(0, a0, b0, a1, b1);
  }

  const int NT = 64;
  for (int tile = 0; tile < NT; ++tile) {
    __syncthreads();
    const int cur = tile & 1;

    bf16x8 a0, b0, a1, b1;
    const bool pf = (tile + 1 < NT);
    if (pf) {
      stageK(tile + 1, cur ^ 1);
      loadV(tile + 1, a0, b0, a1, b1);
    }

    f32x4 st[2];
    #pragma unroll
    for (int half = 0; half < 2; ++half) {
      f32x4 s = {0.f, 0.f, 0.f, 0.f};
      __builtin_amdgcn_s_setprio(1);
      #pragma unroll
      for (int kq = 0; kq < 8; ++kq) {
        const bf16x8 ka = *(const bf16x8*)
            &lK[cur][(half * 16 + qc) * 256 + (((kq * 4 + g) ^ (qc & 7)) << 3)];
        s = MFMA16(ka, qf[kq], s);
      }
      __builtin_amdgcn_s_setprio(0);
      st[half] = s;
    }

    float pm = st[0][0];
    #pragma unroll
    for (int r = 1; r < 4; ++r) pm = fmaxf(pm, st[0][r]);
    #pragma unroll
    for (int r = 0; r < 4; ++r) pm = fmaxf(pm, st[1][r]);
    pm *= scale;
    pm = fmaxf(pm, __shfl_xor(pm, 16, 64));
    pm = fmaxf(pm, __shfl_xor(pm, 32, 64));

    if (!__all(pm <= mrow + 8.0f)) {
      const float mnew = fmaxf(mrow, pm);
      const float corr = exp2f((mrow - mnew) * L2E);
      lrow *= corr;
      #pragma unroll
      for (int f = 0; f < 16; ++f) {
        o[f][0] *= corr; o[f][1] *= corr; o[f][2] *= corr; o[f][3] *= corr;
      }
      mrow = mnew;
    }

    float ladd = 0.0f;
    #pragma unroll
    for (int half = 0; half < 2; ++half) {
      bf16x4 pk;
      #pragma unroll
      for (int r = 0; r < 4; ++r) {
        const float pv = exp2f((st[half][r] * scale - mrow) * L2E);
        ladd += pv;
        pk[r] = (bf16)pv;
      }
      *(bf16x4*)&pl[qc * 40 + half * 16 + g * 4] = pk;
    }
    ladd += __shfl_xor(ladd, 16, 64);
    ladd += __shfl_xor(ladd, 32, 64);
    lrow += ladd;

    LDS_FENCE();

    const bf16x8 pb = *(const bf16x8*)&pl[qc * 40 + g * 8];
    __builtin_amdgcn_s_setprio(1);
    #pragma unroll
    for (int fm = 0; fm < 16; ++fm) {
      const bf16x8 va = *(const bf16x8*)&lVt[cur][(fm * 16 + qc) * 40 + g * 8];
      o[fm] = MFMA16(va, pb, o[fm]);
    }
    __builtin_amdgcn_s_setprio(0);

    if (pf) {
      asm volatile("s_waitcnt vmcnt(0)" ::: "memory");
      __builtin_amdgcn_sched_barrier(0);
      writeVt(cur ^ 1, a0, b0, a1, b1);
    }
  }

  const float inv = 1.0f / lrow;
  const bf16* gp = qgp + (size_t)qrow * 8192 + h * 512 + 256;
  bf16* yp = yb + z * yBatch + (size_t)qrow * 4096 + h * 256;
  #pragma unroll
  for (int fm = 0; fm < 16; ++fm) {
    const int d0 = fm * 16 + g * 4;
    bf16x4 ov;
    #pragma unroll
    for (int r = 0; r < 4; ++r) {
      const float gv = (float)gp[d0 + r];
      const float sig = 1.0f / (1.0f + exp2f(-gv * L2E));
      ov[r] = (bf16)(o[fm][r] * inv * sig);
    }
    *(bf16x4*)&yp[d0] = ov;
  }
}

// ---------------------------------------------------------------------------
extern "C" void kernel_launch(void* const* d_in, const int* in_sizes, int n_in,
                              void* d_out, int out_size, void* d_ws, size_t ws_size,
                              hipStream_t stream) {
  const float* x    = (const float*)d_in[0];
  const float* rope = (const float*)d_in[1];
  const float* wq   = (const float*)d_in[2];
  const float* wk   = (const float*)d_in[3];
  const float* wv   = (const float*)d_in[4];
  const float* wo   = (const float*)d_in[5];
  const float* qnw  = (const float*)d_in[6];
  const float* knw  = (const float*)d_in[7];
  float* out = (float*)d_out;

  if (out_size != 16777216) { write_val<<<1, 64, 0, stream>>>(out, 2000.0f); return; }
  const bool sizes_ok = (n_in == 8) &&
      in_sizes[0] == 16777216 && in_sizes[1] == 262144 &&
      in_sizes[2] == 33554432 && in_sizes[3] == 4194304 &&
      in_sizes[4] == 4194304  && in_sizes[5] == 16777216 &&
      in_sizes[6] == 256      && in_sizes[7] == 256;
  if (!sizes_ok) { write_val<<<1, 64, 0, stream>>>(out, 2500.0f); return; }

  const size_t XS  = 2048ull * 4096;
  const size_t KVS = 2048ull * 1024;
  const size_t QGS = 2048ull * 8192;
  const size_t YS  = 2048ull * 4096;
  const size_t WFIX = (33554432ull + 4194304 + 4194304 + 16777216) * 2;

  const size_t needFull = WFIX + 2 * XS * 2 + 4 * KVS * 2 + 2 * QGS * 2 + 2 * YS * 2;
  auto needT = [&](bool w, int nb, int CHv) -> size_t {
    return (w ? WFIX : 0) + (size_t)nb * XS * 2 + (size_t)nb * KVS * 4
         + (size_t)CHv * 8192 * 2 + (size_t)CHv * 4096 * 2;
  };

  char* ws = (char*)d_ws;

  if (needFull <= ws_size) {
    bf16* wqb = (bf16*)ws;           ws += 33554432ull * 2;
    bf16* wkb = (bf16*)ws;           ws += 4194304ull * 2;
    bf16* wvb = (bf16*)ws;           ws += 4194304ull * 2;
    bf16* wob = (bf16*)ws;           ws += 16777216ull * 2;
    bf16* xb  = (bf16*)ws;           ws += 2 * XS * 2;
    bf16* kbb = (bf16*)ws;           ws += 2 * KVS * 2;
    bf16* vbb = (bf16*)ws;           ws += 2 * KVS * 2;
    bf16* qgc = (bf16*)ws;           ws += 2 * QGS * 2;
    bf16* ycc = (bf16*)ws;

    cvt_pass<<<2048, 256, 0, stream>>>(wq, wqb, 33554432 / 8);
    cvt_pass<<<512,  256, 0, stream>>>(wk, wkb, 4194304 / 8);
    cvt_pass<<<512,  256, 0, stream>>>(wv, wvb, 4194304 / 8);
    cvt_pass<<<1024, 256, 0, stream>>>(wo, wob, 16777216 / 8);
    cvt_pass<<<2048, 256, 0, stream>>>(x, xb, 2 * XS / 8);

    gemm256_3<bf16><<<dim3(40, 8, 2), 512, 0, stream>>>(
        xb, wkb, wvb, wqb, 4, 8, kbb, vbb, qgc,
        4096, XS, KVS, KVS, QGS, 1024, 1024, 8192);

    norm_rope_w<<<4096,  256, 0, stream>>>(kbb, knw, rope, 2, 256, 1024, 0);
    norm_rope_w<<<16384, 256, 0, stream>>>(qgc, qnw, rope, 4, 512, 8192, 0);

    attn_b3<<<dim3(32, 16, 2), 256, 0, stream>>>(
        qgc, kbb, vbb, ycc, QGS, KVS, YS);

    gemm256_3<float><<<dim3(16, 8, 2), 512, 0, stream>>>(
        ycc, wob, wob, wob, 16, 16, out, out, out,
        4096, YS, YS, YS, YS, 4096, 4096, 4096);
    return;
  }

  // ---- fallback tiers ----
  bool useW = true; int nb = 2, CH = 2048;
  while (CH > 256 && needT(useW, nb, CH) > ws_size) CH >>= 1;
  if (needT(useW, nb, CH) > ws_size) {
    useW = false; CH = 2048;
    while (CH > 128 && needT(useW, nb, CH) > ws_size) CH >>= 1;
    if (needT(useW, nb, CH) > ws_size) {
      nb = 1; CH = 2048;
      while (CH > 128 && needT(useW, nb, CH) > ws_size) CH >>= 1;
    }
  }
  if (needT(useW, nb, CH) > ws_size) {
    write_val<<<1, 64, 0, stream>>>(out, 3000.0f);
    return;
  }

  bf16* wqb = nullptr; bf16* wkb = nullptr; bf16* wvb = nullptr; bf16* wob = nullptr;
  if (useW) {
    wqb = (bf16*)ws;               ws += 33554432ull * 2;
    wkb = (bf16*)ws;               ws += 4194304ull * 2;
    wvb = (bf16*)ws;               ws += 4194304ull * 2;
    wob = (bf16*)ws;               ws += 16777216ull * 2;
  }
  bf16* xb  = (bf16*)ws;           ws += (size_t)nb * XS * 2;
  bf16* kbb = (bf16*)ws;           ws += (size_t)nb * KVS * 2;
  bf16* vbb = (bf16*)ws;           ws += (size_t)nb * KVS * 2;
  bf16* qgc = (bf16*)ws;           ws += (size_t)CH * 8192 * 2;
  bf16* ycc = (bf16*)ws;

  if (useW) {
    cvt_pass<<<2048, 256, 0, stream>>>(wq, wqb, 33554432 / 8);
    cvt_pass<<<512,  256, 0, stream>>>(wk, wkb, 4194304 / 8);
    cvt_pass<<<512,  256, 0, stream>>>(wv, wvb, 4194304 / 8);
    cvt_pass<<<1024, 256, 0, stream>>>(wo, wob, 16777216 / 8);
  }

  if (nb == 2) {
    cvt_pass<<<2048, 256, 0, stream>>>(x, xb, 2 * XS / 8);
    if (useW)
      gemm256_3<bf16><<<dim3(8, 8, 2), 512, 0, stream>>>(
          xb, wkb, wvb, wvb, 4, 8, kbb, vbb, vbb,
          4096, XS, KVS, KVS, KVS, 1024, 1024, 1024);
    else
      gemm_bf<bf16, float><<<dim3(16, 16, 2), 256, 0, stream>>>(
          xb, wk, wv, 8, kbb, vbb, 4096, XS, KVS);
    norm_rope_w<<<4096, 256, 0, stream>>>(kbb, knw, rope, 2, 256, 1024, 0);
  }

  for (int b = 0; b < 2; ++b) {
    const int bi = (nb == 2) ? b : 0;
    if (nb == 1) {
      cvt_pass<<<2048, 256, 0, stream>>>(x + (size_t)b * XS, xb, XS / 8);
      if (useW)
        gemm256_3<bf16><<<dim3(8, 8, 1), 512, 0, stream>>>(
            xb, wkb, wvb, wvb, 4, 8, kbb, vbb, vbb,
            4096, 0, 0, 0, 0, 1024, 1024, 1024);
      else
        gemm_bf<bf16, float><<<dim3(16, 16, 1), 256, 0, stream>>>(
            xb, wk, wv, 8, kbb, vbb, 4096, 0, 0);
      norm_rope_w<<<2048, 256, 0, stream>>>(kbb, knw, rope, 2, 256, 1024, 0);
    }
    const bf16* xbb = xb + (size_t)bi * XS;
    bf16* kbbb = kbb + (size_t)bi * KVS;
    bf16* vbbb = vbb + (size_t)bi * KVS;
    for (int c = 0; c < 2048; c += CH) {
      if (useW)
        gemm256_3<bf16><<<dim3(32, CH / 256, 1), 512, 0, stream>>>(
            xbb + (size_t)c * 4096, wqb, wqb, wqb, 32, 32, qgc, qgc, qgc,
            4096, 0, 0, 0, 0, 8192, 8192, 8192);
      else
        gemm_bf<bf16, float><<<dim3(64, CH / 128, 1), 256, 0, stream>>>(
            xbb + (size_t)c * 4096, wq, wq, 64, qgc, qgc, 4096, 0, 0);
      norm_rope_w<<<CH * 4, 256, 0, stream>>>(qgc, qnw, rope, 4, 512, 8192, c);
      attn_b3<<<dim3(CH / 64, 16, 1), 256, 0, stream>>>(
          qgc, kbbb, vbbb, ycc, 0, 0, 0);
      float* outc = out + ((size_t)b * 2048 + c) * 4096;
      if (useW)
        gemm256_3<float><<<dim3(16, CH / 256, 1), 512, 0, stream>>>(
            ycc, wob, wob, wob, 16, 16, outc, outc, outc,
            4096, 0, 0, 0, 0, 4096, 4096, 4096);
      else
        gemm_bf<float, float><<<dim3(32, CH / 128, 1), 256, 0, stream>>>(
            ycc, wo, wo, 32, outc, outc, 4096, 0, 0);
    }
  }
}

// Round 19
// 821.886 us; speedup vs baseline: 1.0251x; 1.0251x over previous
//
#include <hip/hip_runtime.h>
#include <hip/hip_bf16.h>
#include <cstdint>
#include <cstddef>

typedef __bf16 bf16;
typedef __bf16 bf16x8 __attribute__((ext_vector_type(8)));
typedef __bf16 bf16x4 __attribute__((ext_vector_type(4)));
typedef float f32x4 __attribute__((ext_vector_type(4)));

#define MFMA16(a, b, c) __builtin_amdgcn_mfma_f32_16x16x32_bf16((a), (b), (c), 0, 0, 0)
#define GLL16(gp, lp) __builtin_amdgcn_global_load_lds( \
    (const __attribute__((address_space(1))) void*)(gp), \
    (__attribute__((address_space(3))) void*)(lp), 16, 0, 0)

#define LDS_FENCE() do { \
    __builtin_amdgcn_sched_barrier(0); \
    asm volatile("s_waitcnt lgkmcnt(0)" ::: "memory"); \
    __builtin_amdgcn_sched_barrier(0); \
  } while (0)

__device__ __forceinline__ bf16x8 cvt8(const float* f) {
  bf16x8 h;
  #pragma unroll
  for (int j = 0; j < 8; ++j) h[j] = (bf16)f[j];
  return h;
}

__device__ __forceinline__ bf16x8 ldb8(const bf16* p) {
  return *(const bf16x8*)p;
}
__device__ __forceinline__ bf16x8 ldb8(const float* p) {
  float f[8];
  *(f32x4*)&f[0] = *(const f32x4*)p;
  *(f32x4*)&f[4] = *(const f32x4*)(p + 4);
  return cvt8(f);
}

__global__ void write_val(float* o, float v) {
  if (threadIdx.x == 0 && blockIdx.x == 0) o[0] = v;
}

// ---------------------------------------------------------------------------
// fp32 -> bf16 conversion pass. n8 = elems/8.
// ---------------------------------------------------------------------------
__global__ __launch_bounds__(256) void cvt_pass(
    const float* __restrict__ src, bf16* __restrict__ dst, size_t n8)
{
  for (size_t i = (size_t)blockIdx.x * 256 + threadIdx.x; i < n8;
       i += (size_t)gridDim.x * 256) {
    float f[8];
    *(f32x4*)&f[0] = *(const f32x4*)&src[i * 8];
    *(f32x4*)&f[4] = *(const f32x4*)&src[i * 8 + 4];
    *(bf16x8*)&dst[i * 8] = cvt8(f);
  }
}

// ---------------------------------------------------------------------------
// Pipelined 256x256 bf16 GEMM, THREE B/C regions. BK=32, 4 LDS buffers,
// counted vmcnt(8), 8 waves, GLL16 staging, conflict-free swizzle
// (key (row>>1)&3, verified R18: SQ_LDS_BANK_CONFLICT = 0).
// R19: natural block order (R18's XCD remap caused 8x B refetch — reverted);
// single barrier per tile (merged phases: 12 ds_reads -> stage t+3 -> one
// lgkmcnt(0) -> 32 MFMAs). Safety: STAGE(t+3) writes buf (t+3)&3 != t&3;
// buf t&3 is only rewritten by t+4's stage, which is issued after the next
// leading barrier — by then all waves' tile-t ds_reads completed.
// k-accumulation chain unchanged -> bitwise-identical results.
// ---------------------------------------------------------------------------
template <typename CT>
__global__ __launch_bounds__(512, 2) void gemm256_3(
    const bf16* __restrict__ A,
    const bf16* __restrict__ B0, const bf16* __restrict__ B1,
    const bf16* __restrict__ B2, int n1, int n2,
    CT* __restrict__ C0, CT* __restrict__ C1, CT* __restrict__ C2,
    int K, size_t aBatch, size_t cb0, size_t cb1, size_t cb2,
    int ld0, int ld1, int ld2)
{
  __shared__ bf16 lds[4 * 16384];
  const int tid  = threadIdx.x;
  const int wave = tid >> 6, lane = tid & 63;
  const int g = lane >> 4, q = lane & 15;
  const int wm = wave >> 2, wn = wave & 3;
  const int bx = blockIdx.x, by = blockIdx.y, bz = blockIdx.z;

  const int r = (bx < n1) ? 0 : (bx < n2) ? 1 : 2;
  const bf16* Bw = (r == 0) ? B0 : (r == 1) ? B1 : B2;
  CT* C = ((r == 0) ? C0 : (r == 1) ? C1 : C2)
          + (size_t)bz * ((r == 0) ? cb0 : (r == 1) ? cb1 : cb2);
  const int bn = bx - ((r == 0) ? 0 : (r == 1) ? n1 : n2);
  const int ldc = (r == 0) ? ld0 : (r == 1) ? ld1 : ld2;
  const size_t n0 = (size_t)bn * 256;
  const size_t m0 = (size_t)by * 256;
  const bf16* Ap = A + (size_t)bz * aBatch;

  // staging: dest granule tid -> row = i*128 + (tid>>2), slot = tid&3;
  // source slot pre-swizzled by key (row>>1)&3 = (tid>>3)&3.
  const int srow = tid >> 2;
  const int scol = (((tid & 3) ^ ((tid >> 3) & 3)) << 3);
  const int NT = K >> 5;

  f32x4 acc[8][4] = {};

  auto STAGE_A = [&](int t) {
    const int k0 = t << 5;
    char* base = (char*)lds + (size_t)(t & 3) * 32768 + wave * 1024;
    #pragma unroll
    for (int i = 0; i < 2; ++i)
      GLL16(&Ap[(m0 + i * 128 + srow) * (size_t)K + k0 + scol],
            base + i * 8192);
  };
  auto STAGE_B = [&](int t) {
    const int k0 = t << 5;
    char* base = (char*)lds + (size_t)(t & 3) * 32768 + 16384 + wave * 1024;
    #pragma unroll
    for (int i = 0; i < 2; ++i)
      GLL16(&Bw[(n0 + i * 128 + srow) * (size_t)K + k0 + scol],
            base + i * 8192);
  };

  STAGE_A(0); STAGE_B(0);
  STAGE_A(1); STAGE_B(1);
  STAGE_A(2); STAGE_B(2);

  const int rsl = ((g ^ ((q >> 1) & 3)) << 3);   // read slot, key (row>>1)&3

  for (int t = 0; t < NT; ++t) {
    asm volatile("s_waitcnt vmcnt(8)" ::: "memory");
    __builtin_amdgcn_sched_barrier(0);
    __builtin_amdgcn_s_barrier();
    const bf16* lA = lds + (size_t)(t & 3) * 16384;
    const bf16* lB = lA + 8192;

    bf16x8 bfr[4], af[8];
    #pragma unroll
    for (int fn = 0; fn < 4; ++fn)
      bfr[fn] = *(const bf16x8*)&lB[(wn * 64 + fn * 16 + q) * 32 + rsl];
    #pragma unroll
    for (int fm = 0; fm < 8; ++fm)
      af[fm] = *(const bf16x8*)&lA[(wm * 128 + fm * 16 + q) * 32 + rsl];
    if (t + 3 < NT) { STAGE_A(t + 3); STAGE_B(t + 3); }
    asm volatile("s_waitcnt lgkmcnt(0)" ::: "memory");
    __builtin_amdgcn_sched_barrier(0);
    __builtin_amdgcn_s_setprio(1);
    #pragma unroll
    for (int fm = 0; fm < 8; ++fm)
      #pragma unroll
      for (int fn = 0; fn < 4; ++fn)
        acc[fm][fn] = MFMA16(af[fm], bfr[fn], acc[fm][fn]);
    __builtin_amdgcn_s_setprio(0);
  }

  #pragma unroll
  for (int fm = 0; fm < 8; ++fm)
    #pragma unroll
    for (int fn = 0; fn < 4; ++fn)
      #pragma unroll
      for (int rr = 0; rr < 4; ++rr) {
        const size_t row = m0 + wm * 128 + fm * 16 + g * 4 + rr;
        C[row * (size_t)ldc + n0 + wn * 64 + fn * 16 + q] = (CT)acc[fm][fn][rr];
      }
}

// ---------------------------------------------------------------------------
// 128^2 reg-staged GEMM (fp32-B fallback tier only).
// ---------------------------------------------------------------------------
template <typename CT, typename BT>
__global__ __launch_bounds__(256) void gemm_bf(
    const bf16* __restrict__ A,
    const BT* __restrict__ B0, const BT* __restrict__ B1, int nsplit,
    CT* __restrict__ C0, CT* __restrict__ C1,
    int K, size_t aBatch, size_t cBatch)
{
  constexpr int LDST = 72;
  __shared__ bf16 lA[128 * LDST];
  __shared__ bf16 lB[128 * LDST];
  const int tid  = threadIdx.x;
  const int wave = tid >> 6;
  const int lane = tid & 63;
  const int g = lane >> 4, q = lane & 15;
  const bool r0 = (int)blockIdx.x < nsplit;
  const BT* Bw = r0 ? B0 : B1;
  CT* C = (r0 ? C0 : C1) + blockIdx.z * cBatch;
  const int bn = r0 ? blockIdx.x : blockIdx.x - nsplit;
  const int ldc = (r0 ? nsplit : ((int)gridDim.x - nsplit)) * 128;
  const size_t n0 = (size_t)bn * 128;
  const size_t m0 = (size_t)blockIdx.y * 128;
  const bf16* Ap = A + blockIdx.z * aBatch;
  const int wm = wave >> 1, wn = wave & 1;
  const int sr = tid >> 3, sc8 = (tid & 7) << 3;

  f32x4 acc[4][4] = {};

  for (int k0 = 0; k0 < K; k0 += 64) {
    __syncthreads();
    #pragma unroll
    for (int i = 0; i < 4; ++i) {
      const int row = i * 32 + sr;
      *(bf16x8*)&lA[row * LDST + sc8] = ldb8(&Ap[(m0 + row) * (size_t)K + k0 + sc8]);
      *(bf16x8*)&lB[row * LDST + sc8] = ldb8(&Bw[(n0 + row) * (size_t)K + k0 + sc8]);
    }
    __syncthreads();
    #pragma unroll
    for (int kk = 0; kk < 2; ++kk) {
      bf16x8 af[4], bfr[4];
      #pragma unroll
      for (int f = 0; f < 4; ++f) {
        af[f]  = *(const bf16x8*)&lA[(wm * 64 + f * 16 + q) * LDST + kk * 32 + g * 8];
        bfr[f] = *(const bf16x8*)&lB[(wn * 64 + f * 16 + q) * LDST + kk * 32 + g * 8];
      }
      #pragma unroll
      for (int fm = 0; fm < 4; ++fm)
        #pragma unroll
        for (int fn = 0; fn < 4; ++fn)
          acc[fm][fn] = MFMA16(af[fm], bfr[fn], acc[fm][fn]);
    }
  }

  #pragma unroll
  for (int fm = 0; fm < 4; ++fm)
    #pragma unroll
    for (int fn = 0; fn < 4; ++fn)
      #pragma unroll
      for (int r = 0; r < 4; ++r) {
        const size_t row = m0 + wm * 64 + fm * 16 + g * 4 + r;
        C[row * (size_t)ldc + n0 + wn * 64 + fn * 16 + q] = (CT)acc[fm][fn][r];
      }
}

// ---------------------------------------------------------------------------
// Gemma RMSNorm + RoPE, wave per (row, head): 64 lanes x 4 elems, in place.
// ---------------------------------------------------------------------------
__global__ __launch_bounds__(256) void norm_rope_w(
    bf16* __restrict__ data, const float* __restrict__ w,
    const float* __restrict__ ropec, int lnh, int hstride, int rowlen,
    int s_off)
{
  const int lane = threadIdx.x & 63;
  const int wid  = blockIdx.x * 4 + (threadIdx.x >> 6);
  const int m = wid >> lnh;
  const int h = wid & ((1 << lnh) - 1);
  const int s = (s_off + m) & 2047;

  bf16* p = data + (size_t)m * rowlen + h * hstride + lane * 4;
  const bf16x4 xv = *(const bf16x4*)p;
  float x0 = (float)xv[0], x1 = (float)xv[1], x2 = (float)xv[2], x3 = (float)xv[3];
  float ss = x0*x0 + x1*x1 + x2*x2 + x3*x3;
  #pragma unroll
  for (int d = 1; d < 64; d <<= 1) ss += __shfl_xor(ss, d, 64);
  const float rr = rsqrtf(ss * (1.0f / 256.0f) + 1e-6f);
  const f32x4 wv4 = *(const f32x4*)&w[lane * 4];
  x0 *= rr * (1.0f + wv4[0]);
  x1 *= rr * (1.0f + wv4[1]);
  x2 *= rr * (1.0f + wv4[2]);
  x3 *= rr * (1.0f + wv4[3]);

  const float o0 = __shfl_xor(x0, 8, 64);
  const float o1 = __shfl_xor(x1, 8, 64);
  const float o2 = __shfl_xor(x2, 8, 64);
  const float o3 = __shfl_xor(x3, 8, 64);
  if (lane < 16) {
    const int c0 = lane * 4;
    const float* rc = ropec + (size_t)s * 128;
    const float sgn = (lane < 8) ? -1.0f : 1.0f;
    x0 = x0 * rc[c0]     + sgn * o0 * rc[64 + c0];
    x1 = x1 * rc[c0 + 1] + sgn * o1 * rc[64 + c0 + 1];
    x2 = x2 * rc[c0 + 2] + sgn * o2 * rc[64 + c0 + 2];
    x3 = x3 * rc[c0 + 3] + sgn * o3 * rc[64 + c0 + 3];
  }
  bf16x4 ov; ov[0] = (bf16)x0; ov[1] = (bf16)x1; ov[2] = (bf16)x2; ov[3] = (bf16)x3;
  *(bf16x4*)p = ov;
}

// ---------------------------------------------------------------------------
// bf16 MFMA flash attention v3 (R17-verified): double-buffered K (GLL) and
// V^T; per-tile prefetch; defer-max; setprio. 4 waves x 16 Q.
// ---------------------------------------------------------------------------
__global__ __launch_bounds__(256) void attn_b3(
    const bf16* __restrict__ qg, const bf16* __restrict__ kb,
    const bf16* __restrict__ vb, bf16* __restrict__ yb,
    size_t qgBatch, size_t kvBatch, size_t yBatch)
{
  __shared__ bf16 lK[2][32 * 256];
  __shared__ bf16 lVt[2][256 * 40];
  __shared__ bf16 lP[4 * 16 * 40];
  const int tid  = threadIdx.x;
  const int wave = tid >> 6, lane = tid & 63;
  const int g = lane >> 4, qc = lane & 15;
  const int h = blockIdx.y, q0 = blockIdx.x * 64, kvh = h >> 2;
  const int z = blockIdx.z;
  const bf16* qgp = qg + z * qgBatch;
  const bf16* kbase = kb + z * kvBatch + kvh * 256;
  const bf16* vbase = vb + z * kvBatch + kvh * 256;
  const int qrow = q0 + wave * 16 + qc;

  bf16x8 qf[8];
  {
    const bf16* qp = qgp + (size_t)qrow * 8192 + h * 512;
    #pragma unroll
    for (int kq = 0; kq < 8; ++kq)
      qf[kq] = *(const bf16x8*)&qp[kq * 32 + g * 8];
  }

  f32x4 o[16] = {};
  float mrow = -1e30f, lrow = 0.0f;
  const float scale = 0.0625f;
  const float L2E = 1.44269504f;
  const int vp = (tid & 15) * 2, vc = (tid >> 4) * 16;
  bf16* const pl = lP + wave * (16 * 40);
  const int krw = wave * 2 + (lane >> 5);
  const int ksl = lane & 31;

  auto stageK = [&](int tile, int buf) {
    const int t0 = tile * 32;
    #pragma unroll
    for (int i = 0; i < 4; ++i) {
      const int row = i * 8 + krw;
      GLL16(&kbase[(size_t)(t0 + row) * 1024 + ((ksl ^ (row & 7)) << 3)],
            (char*)lK[buf] + i * 4096 + wave * 1024);
    }
  };
  auto loadV = [&](int tile, bf16x8& a0, bf16x8& b0, bf16x8& a1, bf16x8& b1) {
    const bf16* p0 = vbase + (size_t)(tile * 32 + vp) * 1024 + vc;
    a0 = *(const bf16x8*)(p0);
    b0 = *(const bf16x8*)(p0 + 8);
    a1 = *(const bf16x8*)(p0 + 1024);
    b1 = *(const bf16x8*)(p0 + 1032);
  };
  auto writeVt = [&](int buf, const bf16x8& a0, const bf16x8& b0,
                     const bf16x8& a1, const bf16x8& b1) {
    unsigned* dst = (unsigned*)lVt[buf];
    #pragma unroll
    for (int j = 0; j < 8; ++j) {
      const int o0 = (vc + j) * 20 + (vp >> 1);
      const int o1 = (vc + 8 + j) * 20 + (vp >> 1);
      dst[o0] = (unsigned)__builtin_bit_cast(unsigned short, (bf16)a0[j]) |
                ((unsigned)__builtin_bit_cast(unsigned short, (bf16)a1[j]) << 16);
      dst[o1] = (unsigned)__builtin_bit_cast(unsigned short, (bf16)b0[j]) |
                ((unsigned)__builtin_bit_cast(unsigned short, (bf16)b1[j]) << 16);
    }
  };

  {
    bf16x8 a0, b0, a1, b1;
    stageK(0, 0);
    loadV(0, a0, b0, a1, b1);
    asm volatile("s_waitcnt vmcnt(0)" ::: "memory");
    __builtin_amdgcn_sched_barrier(0);
    writeVt(0, a0, b0, a1, b1);
  }

  const int NT = 64;
  for (int tile = 0; tile < NT; ++tile) {
    __syncthreads();
    const int cur = tile & 1;

    bf16x8 a0, b0, a1, b1;
    const bool pf = (tile + 1 < NT);
    if (pf) {
      stageK(tile + 1, cur ^ 1);
      loadV(tile + 1, a0, b0, a1, b1);
    }

    f32x4 st[2];
    #pragma unroll
    for (int half = 0; half < 2; ++half) {
      f32x4 s = {0.f, 0.f, 0.f, 0.f};
      __builtin_amdgcn_s_setprio(1);
      #pragma unroll
      for (int kq = 0; kq < 8; ++kq) {
        const bf16x8 ka = *(const bf16x8*)
            &lK[cur][(half * 16 + qc) * 256 + (((kq * 4 + g) ^ (qc & 7)) << 3)];
        s = MFMA16(ka, qf[kq], s);
      }
      __builtin_amdgcn_s_setprio(0);
      st[half] = s;
    }

    float pm = st[0][0];
    #pragma unroll
    for (int r = 1; r < 4; ++r) pm = fmaxf(pm, st[0][r]);
    #pragma unroll
    for (int r = 0; r < 4; ++r) pm = fmaxf(pm, st[1][r]);
    pm *= scale;
    pm = fmaxf(pm, __shfl_xor(pm, 16, 64));
    pm = fmaxf(pm, __shfl_xor(pm, 32, 64));

    if (!__all(pm <= mrow + 8.0f)) {
      const float mnew = fmaxf(mrow, pm);
      const float corr = exp2f((mrow - mnew) * L2E);
      lrow *= corr;
      #pragma unroll
      for (int f = 0; f < 16; ++f) {
        o[f][0] *= corr; o[f][1] *= corr; o[f][2] *= corr; o[f][3] *= corr;
      }
      mrow = mnew;
    }

    float ladd = 0.0f;
    #pragma unroll
    for (int half = 0; half < 2; ++half) {
      bf16x4 pk;
      #pragma unroll
      for (int r = 0; r < 4; ++r) {
        const float pv = exp2f((st[half][r] * scale - mrow) * L2E);
        ladd += pv;
        pk[r] = (bf16)pv;
      }
      *(bf16x4*)&pl[qc * 40 + half * 16 + g * 4] = pk;
    }
    ladd += __shfl_xor(ladd, 16, 64);
    ladd += __shfl_xor(ladd, 32, 64);
    lrow += ladd;

    LDS_FENCE();

    const bf16x8 pb = *(const bf16x8*)&pl[qc * 40 + g * 8];
    __builtin_amdgcn_s_setprio(1);
    #pragma unroll
    for (int fm = 0; fm < 16; ++fm) {
      const bf16x8 va = *(const bf16x8*)&lVt[cur][(fm * 16 + qc) * 40 + g * 8];
      o[fm] = MFMA16(va, pb, o[fm]);
    }
    __builtin_amdgcn_s_setprio(0);

    if (pf) {
      asm volatile("s_waitcnt vmcnt(0)" ::: "memory");
      __builtin_amdgcn_sched_barrier(0);
      writeVt(cur ^ 1, a0, b0, a1, b1);
    }
  }

  const float inv = 1.0f / lrow;
  const bf16* gp = qgp + (size_t)qrow * 8192 + h * 512 + 256;
  bf16* yp = yb + z * yBatch + (size_t)qrow * 4096 + h * 256;
  #pragma unroll
  for (int fm = 0; fm < 16; ++fm) {
    const int d0 = fm * 16 + g * 4;
    bf16x4 ov;
    #pragma unroll
    for (int r = 0; r < 4; ++r) {
      const float gv = (float)gp[d0 + r];
      const float sig = 1.0f / (1.0f + exp2f(-gv * L2E));
      ov[r] = (bf16)(o[fm][r] * inv * sig);
    }
    *(bf16x4*)&yp[d0] = ov;
  }
}

// ---------------------------------------------------------------------------
extern "C" void kernel_launch(void* const* d_in, const int* in_sizes, int n_in,
                              void* d_out, int out_size, void* d_ws, size_t ws_size,
                              hipStream_t stream) {
  const float* x    = (const float*)d_in[0];
  const float* rope = (const float*)d_in[1];
  const float* wq   = (const float*)d_in[2];
  const float* wk   = (const float*)d_in[3];
  const float* wv   = (const float*)d_in[4];
  const float* wo   = (const float*)d_in[5];
  const float* qnw  = (const float*)d_in[6];
  const float* knw  = (const float*)d_in[7];
  float* out = (float*)d_out;

  if (out_size != 16777216) { write_val<<<1, 64, 0, stream>>>(out, 2000.0f); return; }
  const bool sizes_ok = (n_in == 8) &&
      in_sizes[0] == 16777216 && in_sizes[1] == 262144 &&
      in_sizes[2] == 33554432 && in_sizes[3] == 4194304 &&
      in_sizes[4] == 4194304  && in_sizes[5] == 16777216 &&
      in_sizes[6] == 256      && in_sizes[7] == 256;
  if (!sizes_ok) { write_val<<<1, 64, 0, stream>>>(out, 2500.0f); return; }

  const size_t XS  = 2048ull * 4096;
  const size_t KVS = 2048ull * 1024;
  const size_t QGS = 2048ull * 8192;
  const size_t YS  = 2048ull * 4096;
  const size_t WFIX = (33554432ull + 4194304 + 4194304 + 16777216) * 2;

  const size_t needFull = WFIX + 2 * XS * 2 + 4 * KVS * 2 + 2 * QGS * 2 + 2 * YS * 2;
  auto needT = [&](bool w, int nb, int CHv) -> size_t {
    return (w ? WFIX : 0) + (size_t)nb * XS * 2 + (size_t)nb * KVS * 4
         + (size_t)CHv * 8192 * 2 + (size_t)CHv * 4096 * 2;
  };

  char* ws = (char*)d_ws;

  if (needFull <= ws_size) {
    bf16* wqb = (bf16*)ws;           ws += 33554432ull * 2;
    bf16* wkb = (bf16*)ws;           ws += 4194304ull * 2;
    bf16* wvb = (bf16*)ws;           ws += 4194304ull * 2;
    bf16* wob = (bf16*)ws;           ws += 16777216ull * 2;
    bf16* xb  = (bf16*)ws;           ws += 2 * XS * 2;
    bf16* kbb = (bf16*)ws;           ws += 2 * KVS * 2;
    bf16* vbb = (bf16*)ws;           ws += 2 * KVS * 2;
    bf16* qgc = (bf16*)ws;           ws += 2 * QGS * 2;
    bf16* ycc = (bf16*)ws;

    cvt_pass<<<2048, 256, 0, stream>>>(wq, wqb, 33554432 / 8);
    cvt_pass<<<512,  256, 0, stream>>>(wk, wkb, 4194304 / 8);
    cvt_pass<<<512,  256, 0, stream>>>(wv, wvb, 4194304 / 8);
    cvt_pass<<<1024, 256, 0, stream>>>(wo, wob, 16777216 / 8);
    cvt_pass<<<2048, 256, 0, stream>>>(x, xb, 2 * XS / 8);

    gemm256_3<bf16><<<dim3(40, 8, 2), 512, 0, stream>>>(
        xb, wkb, wvb, wqb, 4, 8, kbb, vbb, qgc,
        4096, XS, KVS, KVS, QGS, 1024, 1024, 8192);

    norm_rope_w<<<4096,  256, 0, stream>>>(kbb, knw, rope, 2, 256, 1024, 0);
    norm_rope_w<<<16384, 256, 0, stream>>>(qgc, qnw, rope, 4, 512, 8192, 0);

    attn_b3<<<dim3(32, 16, 2), 256, 0, stream>>>(
        qgc, kbb, vbb, ycc, QGS, KVS, YS);

    gemm256_3<float><<<dim3(16, 8, 2), 512, 0, stream>>>(
        ycc, wob, wob, wob, 16, 16, out, out, out,
        4096, YS, YS, YS, YS, 4096, 4096, 4096);
    return;
  }

  // ---- fallback tiers ----
  bool useW = true; int nb = 2, CH = 2048;
  while (CH > 256 && needT(useW, nb, CH) > ws_size) CH >>= 1;
  if (needT(useW, nb, CH) > ws_size) {
    useW = false; CH = 2048;
    while (CH > 128 && needT(useW, nb, CH) > ws_size) CH >>= 1;
    if (needT(useW, nb, CH) > ws_size) {
      nb = 1; CH = 2048;
      while (CH > 128 && needT(useW, nb, CH) > ws_size) CH >>= 1;
    }
  }
  if (needT(useW, nb, CH) > ws_size) {
    write_val<<<1, 64, 0, stream>>>(out, 3000.0f);
    return;
  }

  bf16* wqb = nullptr; bf16* wkb = nullptr; bf16* wvb = nullptr; bf16* wob = nullptr;
  if (useW) {
    wqb = (bf16*)ws;               ws += 33554432ull * 2;
    wkb = (bf16*)ws;               ws += 4194304ull * 2;
    wvb = (bf16*)ws;               ws += 4194304ull * 2;
    wob = (bf16*)ws;               ws += 16777216ull * 2;
  }
  bf16* xb  = (bf16*)ws;           ws += (size_t)nb * XS * 2;
  bf16* kbb = (bf16*)ws;           ws += (size_t)nb * KVS * 2;
  bf16* vbb = (bf16*)ws;           ws += (size_t)nb * KVS * 2;
  bf16* qgc = (bf16*)ws;           ws += (size_t)CH * 8192 * 2;
  bf16* ycc = (bf16*)ws;

  if (useW) {
    cvt_pass<<<2048, 256, 0, stream>>>(wq, wqb, 33554432 / 8);
    cvt_pass<<<512,  256, 0, stream>>>(wk, wkb, 4194304 / 8);
    cvt_pass<<<512,  256, 0, stream>>>(wv, wvb, 4194304 / 8);
    cvt_pass<<<1024, 256, 0, stream>>>(wo, wob, 16777216 / 8);
  }

  if (nb == 2) {
    cvt_pass<<<2048, 256, 0, stream>>>(x, xb, 2 * XS / 8);
    if (useW)
      gemm256_3<bf16><<<dim3(8, 8, 2), 512, 0, stream>>>(
          xb, wkb, wvb, wvb, 4, 8, kbb, vbb, vbb,
          4096, XS, KVS, KVS, KVS, 1024, 1024, 1024);
    else
      gemm_bf<bf16, float><<<dim3(16, 16, 2), 256, 0, stream>>>(
          xb, wk, wv, 8, kbb, vbb, 4096, XS, KVS);
    norm_rope_w<<<4096, 256, 0, stream>>>(kbb, knw, rope, 2, 256, 1024, 0);
  }

  for (int b = 0; b < 2; ++b) {
    const int bi = (nb == 2) ? b : 0;
    if (nb == 1) {
      cvt_pass<<<2048, 256, 0, stream>>>(x + (size_t)b * XS, xb, XS / 8);
      if (useW)
        gemm256_3<bf16><<<dim3(8, 8, 1), 512, 0, stream>>>(
            xb, wkb, wvb, wvb, 4, 8, kbb, vbb, vbb,
            4096, 0, 0, 0, 0, 1024, 1024, 1024);
      else
        gemm_bf<bf16, float><<<dim3(16, 16, 1), 256, 0, stream>>>(
            xb, wk, wv, 8, kbb, vbb, 4096, 0, 0);
      norm_rope_w<<<2048, 256, 0, stream>>>(kbb, knw, rope, 2, 256, 1024, 0);
    }
    const bf16* xbb = xb + (size_t)bi * XS;
    bf16* kbbb = kbb + (size_t)bi * KVS;
    bf16* vbbb = vbb + (size_t)bi * KVS;
    for (int c = 0; c < 2048; c += CH) {
      if (useW)
        gemm256_3<bf16><<<dim3(32, CH / 256, 1), 512, 0, stream>>>(
            xbb + (size_t)c * 4096, wqb, wqb, wqb, 32, 32, qgc, qgc, qgc,
            4096, 0, 0, 0, 0, 8192, 8192, 8192);
      else
        gemm_bf<bf16, float><<<dim3(64, CH / 128, 1), 256, 0, stream>>>(
            xbb + (size_t)c * 4096, wq, wq, 64, qgc, qgc, 4096, 0, 0);
      norm_rope_w<<<CH * 4, 256, 0, stream>>>(qgc, qnw, rope, 4, 512, 8192, c);
      attn_b3<<<dim3(CH / 64, 16, 1), 256, 0, stream>>>(
          qgc, kbbb, vbbb, ycc, 0, 0, 0);
      float* outc = out + ((size_t)b * 2048 + c) * 4096;
      if (useW)
        gemm256_3<float><<<dim3(16, CH / 256, 1), 512, 0, stream>>>(
            ycc, wob, wob, wob, 16, 16, outc, outc, outc,
            4096, 0, 0, 0, 0, 4096, 4096, 4096);
      else
        gemm_bf<float, float><<<dim3(32, CH / 128, 1), 256, 0, stream>>>(
            ycc, wo, wo, 32, outc, outc, 4096, 0, 0);
    }
  }
}

// Round 21
// 820.695 us; speedup vs baseline: 1.0266x; 1.0015x over previous
//
#include <hip/hip_runtime.h>
#include <hip/hip_bf16.h>
#include <cstdint>
#include <cstddef>

typedef __bf16 bf16;
typedef __bf16 bf16x8 __attribute__((ext_vector_type(8)));
typedef __bf16 bf16x4 __attribute__((ext_vector_type(4)));
typedef float f32x4 __attribute__((ext_vector_type(4)));

#define MFMA16(a, b, c) __builtin_amdgcn_mfma_f32_16x16x32_bf16((a), (b), (c), 0, 0, 0)
#define GLL16(gp, lp) __builtin_amdgcn_global_load_lds( \
    (const __attribute__((address_space(1))) void*)(gp), \
    (__attribute__((address_space(3))) void*)(lp), 16, 0, 0)

#define LDS_FENCE() do { \
    __builtin_amdgcn_sched_barrier(0); \
    asm volatile("s_waitcnt lgkmcnt(0)" ::: "memory"); \
    __builtin_amdgcn_sched_barrier(0); \
  } while (0)

__device__ __forceinline__ bf16x8 cvt8(const float* f) {
  bf16x8 h;
  #pragma unroll
  for (int j = 0; j < 8; ++j) h[j] = (bf16)f[j];
  return h;
}

__device__ __forceinline__ bf16x8 ldb8(const bf16* p) {
  return *(const bf16x8*)p;
}
__device__ __forceinline__ bf16x8 ldb8(const float* p) {
  float f[8];
  *(f32x4*)&f[0] = *(const f32x4*)p;
  *(f32x4*)&f[4] = *(const f32x4*)(p + 4);
  return cvt8(f);
}

__global__ void write_val(float* o, float v) {
  if (threadIdx.x == 0 && blockIdx.x == 0) o[0] = v;
}

// ---------------------------------------------------------------------------
// fp32 -> bf16 conversion pass. n8 = elems/8.
// ---------------------------------------------------------------------------
__global__ __launch_bounds__(256) void cvt_pass(
    const float* __restrict__ src, bf16* __restrict__ dst, size_t n8)
{
  for (size_t i = (size_t)blockIdx.x * 256 + threadIdx.x; i < n8;
       i += (size_t)gridDim.x * 256) {
    float f[8];
    *(f32x4*)&f[0] = *(const f32x4*)&src[i * 8];
    *(f32x4*)&f[4] = *(const f32x4*)&src[i * 8 + 4];
    *(bf16x8*)&dst[i * 8] = cvt8(f);
  }
}

// ---------------------------------------------------------------------------
// Pipelined 256x256 bf16 GEMM, THREE B/C regions. BK=32, 4 LDS buffers,
// counted vmcnt(8), 8 waves, GLL16 staging, conflict-free swizzle
// (key (row>>1)&3, verified R18: SQ_LDS_BANK_CONFLICT = 0).
// R19 schedule (replay-validated): natural block order; single barrier per
// tile; 12 ds_reads -> stage t+3 -> one lgkmcnt(0) -> 32 MFMAs.
// (R20's counted-lgkmcnt sub-phases raced under graph replay — reverted.)
// Safety: STAGE(t+3) writes buf (t+3)&3 != t&3; buf t&3 is only rewritten
// by t+4's stage, issued after the next leading barrier — by then all
// waves' tile-t ds_reads completed (they precede each wave's lgkmcnt(0)).
// ---------------------------------------------------------------------------
template <typename CT>
__global__ __launch_bounds__(512, 2) void gemm256_3(
    const bf16* __restrict__ A,
    const bf16* __restrict__ B0, const bf16* __restrict__ B1,
    const bf16* __restrict__ B2, int n1, int n2,
    CT* __restrict__ C0, CT* __restrict__ C1, CT* __restrict__ C2,
    int K, size_t aBatch, size_t cb0, size_t cb1, size_t cb2,
    int ld0, int ld1, int ld2)
{
  __shared__ bf16 lds[4 * 16384];
  const int tid  = threadIdx.x;
  const int wave = tid >> 6, lane = tid & 63;
  const int g = lane >> 4, q = lane & 15;
  const int wm = wave >> 2, wn = wave & 3;
  const int bx = blockIdx.x, by = blockIdx.y, bz = blockIdx.z;

  const int r = (bx < n1) ? 0 : (bx < n2) ? 1 : 2;
  const bf16* Bw = (r == 0) ? B0 : (r == 1) ? B1 : B2;
  CT* C = ((r == 0) ? C0 : (r == 1) ? C1 : C2)
          + (size_t)bz * ((r == 0) ? cb0 : (r == 1) ? cb1 : cb2);
  const int bn = bx - ((r == 0) ? 0 : (r == 1) ? n1 : n2);
  const int ldc = (r == 0) ? ld0 : (r == 1) ? ld1 : ld2;
  const size_t n0 = (size_t)bn * 256;
  const size_t m0 = (size_t)by * 256;
  const bf16* Ap = A + (size_t)bz * aBatch;

  // staging: dest granule tid -> row = i*128 + (tid>>2), slot = tid&3;
  // source slot pre-swizzled by key (row>>1)&3 = (tid>>3)&3.
  const int srow = tid >> 2;
  const int scol = (((tid & 3) ^ ((tid >> 3) & 3)) << 3);
  const int NT = K >> 5;

  f32x4 acc[8][4] = {};

  auto STAGE_A = [&](int t) {
    const int k0 = t << 5;
    char* base = (char*)lds + (size_t)(t & 3) * 32768 + wave * 1024;
    #pragma unroll
    for (int i = 0; i < 2; ++i)
      GLL16(&Ap[(m0 + i * 128 + srow) * (size_t)K + k0 + scol],
            base + i * 8192);
  };
  auto STAGE_B = [&](int t) {
    const int k0 = t << 5;
    char* base = (char*)lds + (size_t)(t & 3) * 32768 + 16384 + wave * 1024;
    #pragma unroll
    for (int i = 0; i < 2; ++i)
      GLL16(&Bw[(n0 + i * 128 + srow) * (size_t)K + k0 + scol],
            base + i * 8192);
  };

  STAGE_A(0); STAGE_B(0);
  STAGE_A(1); STAGE_B(1);
  STAGE_A(2); STAGE_B(2);

  const int rsl = ((g ^ ((q >> 1) & 3)) << 3);   // read slot, key (row>>1)&3

  for (int t = 0; t < NT; ++t) {
    asm volatile("s_waitcnt vmcnt(8)" ::: "memory");
    __builtin_amdgcn_sched_barrier(0);
    __builtin_amdgcn_s_barrier();
    const bf16* lA = lds + (size_t)(t & 3) * 16384;
    const bf16* lB = lA + 8192;

    bf16x8 bfr[4], af[8];
    #pragma unroll
    for (int fn = 0; fn < 4; ++fn)
      bfr[fn] = *(const bf16x8*)&lB[(wn * 64 + fn * 16 + q) * 32 + rsl];
    #pragma unroll
    for (int fm = 0; fm < 8; ++fm)
      af[fm] = *(const bf16x8*)&lA[(wm * 128 + fm * 16 + q) * 32 + rsl];
    if (t + 3 < NT) { STAGE_A(t + 3); STAGE_B(t + 3); }
    asm volatile("s_waitcnt lgkmcnt(0)" ::: "memory");
    __builtin_amdgcn_sched_barrier(0);
    __builtin_amdgcn_s_setprio(1);
    #pragma unroll
    for (int fm = 0; fm < 8; ++fm)
      #pragma unroll
      for (int fn = 0; fn < 4; ++fn)
        acc[fm][fn] = MFMA16(af[fm], bfr[fn], acc[fm][fn]);
    __builtin_amdgcn_s_setprio(0);
  }

  #pragma unroll
  for (int fm = 0; fm < 8; ++fm)
    #pragma unroll
    for (int fn = 0; fn < 4; ++fn)
      #pragma unroll
      for (int rr = 0; rr < 4; ++rr) {
        const size_t row = m0 + wm * 128 + fm * 16 + g * 4 + rr;
        C[row * (size_t)ldc + n0 + wn * 64 + fn * 16 + q] = (CT)acc[fm][fn][rr];
      }
}

// ---------------------------------------------------------------------------
// 128^2 reg-staged GEMM (fp32-B fallback tier only).
// ---------------------------------------------------------------------------
template <typename CT, typename BT>
__global__ __launch_bounds__(256) void gemm_bf(
    const bf16* __restrict__ A,
    const BT* __restrict__ B0, const BT* __restrict__ B1, int nsplit,
    CT* __restrict__ C0, CT* __restrict__ C1,
    int K, size_t aBatch, size_t cBatch)
{
  constexpr int LDST = 72;
  __shared__ bf16 lA[128 * LDST];
  __shared__ bf16 lB[128 * LDST];
  const int tid  = threadIdx.x;
  const int wave = tid >> 6;
  const int lane = tid & 63;
  const int g = lane >> 4, q = lane & 15;
  const bool r0 = (int)blockIdx.x < nsplit;
  const BT* Bw = r0 ? B0 : B1;
  CT* C = (r0 ? C0 : C1) + blockIdx.z * cBatch;
  const int bn = r0 ? blockIdx.x : blockIdx.x - nsplit;
  const int ldc = (r0 ? nsplit : ((int)gridDim.x - nsplit)) * 128;
  const size_t n0 = (size_t)bn * 128;
  const size_t m0 = (size_t)blockIdx.y * 128;
  const bf16* Ap = A + blockIdx.z * aBatch;
  const int wm = wave >> 1, wn = wave & 1;
  const int sr = tid >> 3, sc8 = (tid & 7) << 3;

  f32x4 acc[4][4] = {};

  for (int k0 = 0; k0 < K; k0 += 64) {
    __syncthreads();
    #pragma unroll
    for (int i = 0; i < 4; ++i) {
      const int row = i * 32 + sr;
      *(bf16x8*)&lA[row * LDST + sc8] = ldb8(&Ap[(m0 + row) * (size_t)K + k0 + sc8]);
      *(bf16x8*)&lB[row * LDST + sc8] = ldb8(&Bw[(n0 + row) * (size_t)K + k0 + sc8]);
    }
    __syncthreads();
    #pragma unroll
    for (int kk = 0; kk < 2; ++kk) {
      bf16x8 af[4], bfr[4];
      #pragma unroll
      for (int f = 0; f < 4; ++f) {
        af[f]  = *(const bf16x8*)&lA[(wm * 64 + f * 16 + q) * LDST + kk * 32 + g * 8];
        bfr[f] = *(const bf16x8*)&lB[(wn * 64 + f * 16 + q) * LDST + kk * 32 + g * 8];
      }
      #pragma unroll
      for (int fm = 0; fm < 4; ++fm)
        #pragma unroll
        for (int fn = 0; fn < 4; ++fn)
          acc[fm][fn] = MFMA16(af[fm], bfr[fn], acc[fm][fn]);
    }
  }

  #pragma unroll
  for (int fm = 0; fm < 4; ++fm)
    #pragma unroll
    for (int fn = 0; fn < 4; ++fn)
      #pragma unroll
      for (int r = 0; r < 4; ++r) {
        const size_t row = m0 + wm * 64 + fm * 16 + g * 4 + r;
        C[row * (size_t)ldc + n0 + wn * 64 + fn * 16 + q] = (CT)acc[fm][fn][r];
      }
}

// ---------------------------------------------------------------------------
// Gemma RMSNorm + RoPE, wave per (row, head): 64 lanes x 4 elems, in place.
// ---------------------------------------------------------------------------
__global__ __launch_bounds__(256) void norm_rope_w(
    bf16* __restrict__ data, const float* __restrict__ w,
    const float* __restrict__ ropec, int lnh, int hstride, int rowlen,
    int s_off)
{
  const int lane = threadIdx.x & 63;
  const int wid  = blockIdx.x * 4 + (threadIdx.x >> 6);
  const int m = wid >> lnh;
  const int h = wid & ((1 << lnh) - 1);
  const int s = (s_off + m) & 2047;

  bf16* p = data + (size_t)m * rowlen + h * hstride + lane * 4;
  const bf16x4 xv = *(const bf16x4*)p;
  float x0 = (float)xv[0], x1 = (float)xv[1], x2 = (float)xv[2], x3 = (float)xv[3];
  float ss = x0*x0 + x1*x1 + x2*x2 + x3*x3;
  #pragma unroll
  for (int d = 1; d < 64; d <<= 1) ss += __shfl_xor(ss, d, 64);
  const float rr = rsqrtf(ss * (1.0f / 256.0f) + 1e-6f);
  const f32x4 wv4 = *(const f32x4*)&w[lane * 4];
  x0 *= rr * (1.0f + wv4[0]);
  x1 *= rr * (1.0f + wv4[1]);
  x2 *= rr * (1.0f + wv4[2]);
  x3 *= rr * (1.0f + wv4[3]);

  const float o0 = __shfl_xor(x0, 8, 64);
  const float o1 = __shfl_xor(x1, 8, 64);
  const float o2 = __shfl_xor(x2, 8, 64);
  const float o3 = __shfl_xor(x3, 8, 64);
  if (lane < 16) {
    const int c0 = lane * 4;
    const float* rc = ropec + (size_t)s * 128;
    const float sgn = (lane < 8) ? -1.0f : 1.0f;
    x0 = x0 * rc[c0]     + sgn * o0 * rc[64 + c0];
    x1 = x1 * rc[c0 + 1] + sgn * o1 * rc[64 + c0 + 1];
    x2 = x2 * rc[c0 + 2] + sgn * o2 * rc[64 + c0 + 2];
    x3 = x3 * rc[c0 + 3] + sgn * o3 * rc[64 + c0 + 3];
  }
  bf16x4 ov; ov[0] = (bf16)x0; ov[1] = (bf16)x1; ov[2] = (bf16)x2; ov[3] = (bf16)x3;
  *(bf16x4*)p = ov;
}

// ---------------------------------------------------------------------------
// bf16 MFMA flash attention v3 (R17-verified): double-buffered K (GLL) and
// V^T; per-tile prefetch; defer-max; setprio. 4 waves x 16 Q.
// ---------------------------------------------------------------------------
__global__ __launch_bounds__(256) void attn_b3(
    const bf16* __restrict__ qg, const bf16* __restrict__ kb,
    const bf16* __restrict__ vb, bf16* __restrict__ yb,
    size_t qgBatch, size_t kvBatch, size_t yBatch)
{
  __shared__ bf16 lK[2][32 * 256];
  __shared__ bf16 lVt[2][256 * 40];
  __shared__ bf16 lP[4 * 16 * 40];
  const int tid  = threadIdx.x;
  const int wave = tid >> 6, lane = tid & 63;
  const int g = lane >> 4, qc = lane & 15;
  const int h = blockIdx.y, q0 = blockIdx.x * 64, kvh = h >> 2;
  const int z = blockIdx.z;
  const bf16* qgp = qg + z * qgBatch;
  const bf16* kbase = kb + z * kvBatch + kvh * 256;
  const bf16* vbase = vb + z * kvBatch + kvh * 256;
  const int qrow = q0 + wave * 16 + qc;

  bf16x8 qf[8];
  {
    const bf16* qp = qgp + (size_t)qrow * 8192 + h * 512;
    #pragma unroll
    for (int kq = 0; kq < 8; ++kq)
      qf[kq] = *(const bf16x8*)&qp[kq * 32 + g * 8];
  }

  f32x4 o[16] = {};
  float mrow = -1e30f, lrow = 0.0f;
  const float scale = 0.0625f;
  const float L2E = 1.44269504f;
  const int vp = (tid & 15) * 2, vc = (tid >> 4) * 16;
  bf16* const pl = lP + wave * (16 * 40);
  const int krw = wave * 2 + (lane >> 5);
  const int ksl = lane & 31;

  auto stageK = [&](int tile, int buf) {
    const int t0 = tile * 32;
    #pragma unroll
    for (int i = 0; i < 4; ++i) {
      const int row = i * 8 + krw;
      GLL16(&kbase[(size_t)(t0 + row) * 1024 + ((ksl ^ (row & 7)) << 3)],
            (char*)lK[buf] + i * 4096 + wave * 1024);
    }
  };
  auto loadV = [&](int tile, bf16x8& a0, bf16x8& b0, bf16x8& a1, bf16x8& b1) {
    const bf16* p0 = vbase + (size_t)(tile * 32 + vp) * 1024 + vc;
    a0 = *(const bf16x8*)(p0);
    b0 = *(const bf16x8*)(p0 + 8);
    a1 = *(const bf16x8*)(p0 + 1024);
    b1 = *(const bf16x8*)(p0 + 1032);
  };
  auto writeVt = [&](int buf, const bf16x8& a0, const bf16x8& b0,
                     const bf16x8& a1, const bf16x8& b1) {
    unsigned* dst = (unsigned*)lVt[buf];
    #pragma unroll
    for (int j = 0; j < 8; ++j) {
      const int o0 = (vc + j) * 20 + (vp >> 1);
      const int o1 = (vc + 8 + j) * 20 + (vp >> 1);
      dst[o0] = (unsigned)__builtin_bit_cast(unsigned short, (bf16)a0[j]) |
                ((unsigned)__builtin_bit_cast(unsigned short, (bf16)a1[j]) << 16);
      dst[o1] = (unsigned)__builtin_bit_cast(unsigned short, (bf16)b0[j]) |
                ((unsigned)__builtin_bit_cast(unsigned short, (bf16)b1[j]) << 16);
    }
  };

  {
    bf16x8 a0, b0, a1, b1;
    stageK(0, 0);
    loadV(0, a0, b0, a1, b1);
    asm volatile("s_waitcnt vmcnt(0)" ::: "memory");
    __builtin_amdgcn_sched_barrier(0);
    writeVt(0, a0, b0, a1, b1);
  }

  const int NT = 64;
  for (int tile = 0; tile < NT; ++tile) {
    __syncthreads();
    const int cur = tile & 1;

    bf16x8 a0, b0, a1, b1;
    const bool pf = (tile + 1 < NT);
    if (pf) {
      stageK(tile + 1, cur ^ 1);
      loadV(tile + 1, a0, b0, a1, b1);
    }

    f32x4 st[2];
    #pragma unroll
    for (int half = 0; half < 2; ++half) {
      f32x4 s = {0.f, 0.f, 0.f, 0.f};
      __builtin_amdgcn_s_setprio(1);
      #pragma unroll
      for (int kq = 0; kq < 8; ++kq) {
        const bf16x8 ka = *(const bf16x8*)
            &lK[cur][(half * 16 + qc) * 256 + (((kq * 4 + g) ^ (qc & 7)) << 3)];
        s = MFMA16(ka, qf[kq], s);
      }
      __builtin_amdgcn_s_setprio(0);
      st[half] = s;
    }

    float pm = st[0][0];
    #pragma unroll
    for (int r = 1; r < 4; ++r) pm = fmaxf(pm, st[0][r]);
    #pragma unroll
    for (int r = 0; r < 4; ++r) pm = fmaxf(pm, st[1][r]);
    pm *= scale;
    pm = fmaxf(pm, __shfl_xor(pm, 16, 64));
    pm = fmaxf(pm, __shfl_xor(pm, 32, 64));

    if (!__all(pm <= mrow + 8.0f)) {
      const float mnew = fmaxf(mrow, pm);
      const float corr = exp2f((mrow - mnew) * L2E);
      lrow *= corr;
      #pragma unroll
      for (int f = 0; f < 16; ++f) {
        o[f][0] *= corr; o[f][1] *= corr; o[f][2] *= corr; o[f][3] *= corr;
      }
      mrow = mnew;
    }

    float ladd = 0.0f;
    #pragma unroll
    for (int half = 0; half < 2; ++half) {
      bf16x4 pk;
      #pragma unroll
      for (int r = 0; r < 4; ++r) {
        const float pv = exp2f((st[half][r] * scale - mrow) * L2E);
        ladd += pv;
        pk[r] = (bf16)pv;
      }
      *(bf16x4*)&pl[qc * 40 + half * 16 + g * 4] = pk;
    }
    ladd += __shfl_xor(ladd, 16, 64);
    ladd += __shfl_xor(ladd, 32, 64);
    lrow += ladd;

    LDS_FENCE();

    const bf16x8 pb = *(const bf16x8*)&pl[qc * 40 + g * 8];
    __builtin_amdgcn_s_setprio(1);
    #pragma unroll
    for (int fm = 0; fm < 16; ++fm) {
      const bf16x8 va = *(const bf16x8*)&lVt[cur][(fm * 16 + qc) * 40 + g * 8];
      o[fm] = MFMA16(va, pb, o[fm]);
    }
    __builtin_amdgcn_s_setprio(0);

    if (pf) {
      asm volatile("s_waitcnt vmcnt(0)" ::: "memory");
      __builtin_amdgcn_sched_barrier(0);
      writeVt(cur ^ 1, a0, b0, a1, b1);
    }
  }

  const float inv = 1.0f / lrow;
  const bf16* gp = qgp + (size_t)qrow * 8192 + h * 512 + 256;
  bf16* yp = yb + z * yBatch + (size_t)qrow * 4096 + h * 256;
  #pragma unroll
  for (int fm = 0; fm < 16; ++fm) {
    const int d0 = fm * 16 + g * 4;
    bf16x4 ov;
    #pragma unroll
    for (int r = 0; r < 4; ++r) {
      const float gv = (float)gp[d0 + r];
      const float sig = 1.0f / (1.0f + exp2f(-gv * L2E));
      ov[r] = (bf16)(o[fm][r] * inv * sig);
    }
    *(bf16x4*)&yp[d0] = ov;
  }
}

// ---------------------------------------------------------------------------
extern "C" void kernel_launch(void* const* d_in, const int* in_sizes, int n_in,
                              void* d_out, int out_size, void* d_ws, size_t ws_size,
                              hipStream_t stream) {
  const float* x    = (const float*)d_in[0];
  const float* rope = (const float*)d_in[1];
  const float* wq   = (const float*)d_in[2];
  const float* wk   = (const float*)d_in[3];
  const float* wv   = (const float*)d_in[4];
  const float* wo   = (const float*)d_in[5];
  const float* qnw  = (const float*)d_in[6];
  const float* knw  = (const float*)d_in[7];
  float* out = (float*)d_out;

  if (out_size != 16777216) { write_val<<<1, 64, 0, stream>>>(out, 2000.0f); return; }
  const bool sizes_ok = (n_in == 8) &&
      in_sizes[0] == 16777216 && in_sizes[1] == 262144 &&
      in_sizes[2] == 33554432 && in_sizes[3] == 4194304 &&
      in_sizes[4] == 4194304  && in_sizes[5] == 16777216 &&
      in_sizes[6] == 256      && in_sizes[7] == 256;
  if (!sizes_ok) { write_val<<<1, 64, 0, stream>>>(out, 2500.0f); return; }

  const size_t XS  = 2048ull * 4096;
  const size_t KVS = 2048ull * 1024;
  const size_t QGS = 2048ull * 8192;
  const size_t YS  = 2048ull * 4096;
  const size_t WFIX = (33554432ull + 4194304 + 4194304 + 16777216) * 2;

  const size_t needFull = WFIX + 2 * XS * 2 + 4 * KVS * 2 + 2 * QGS * 2 + 2 * YS * 2;
  auto needT = [&](bool w, int nb, int CHv) -> size_t {
    return (w ? WFIX : 0) + (size_t)nb * XS * 2 + (size_t)nb * KVS * 4
         + (size_t)CHv * 8192 * 2 + (size_t)CHv * 4096 * 2;
  };

  char* ws = (char*)d_ws;

  if (needFull <= ws_size) {
    bf16* wqb = (bf16*)ws;           ws += 33554432ull * 2;
    bf16* wkb = (bf16*)ws;           ws += 4194304ull * 2;
    bf16* wvb = (bf16*)ws;           ws += 4194304ull * 2;
    bf16* wob = (bf16*)ws;           ws += 16777216ull * 2;
    bf16* xb  = (bf16*)ws;           ws += 2 * XS * 2;
    bf16* kbb = (bf16*)ws;           ws += 2 * KVS * 2;
    bf16* vbb = (bf16*)ws;           ws += 2 * KVS * 2;
    bf16* qgc = (bf16*)ws;           ws += 2 * QGS * 2;
    bf16* ycc = (bf16*)ws;

    cvt_pass<<<2048, 256, 0, stream>>>(wq, wqb, 33554432 / 8);
    cvt_pass<<<512,  256, 0, stream>>>(wk, wkb, 4194304 / 8);
    cvt_pass<<<512,  256, 0, stream>>>(wv, wvb, 4194304 / 8);
    cvt_pass<<<1024, 256, 0, stream>>>(wo, wob, 16777216 / 8);
    cvt_pass<<<2048, 256, 0, stream>>>(x, xb, 2 * XS / 8);

    gemm256_3<bf16><<<dim3(40, 8, 2), 512, 0, stream>>>(
        xb, wkb, wvb, wqb, 4, 8, kbb, vbb, qgc,
        4096, XS, KVS, KVS, QGS, 1024, 1024, 8192);

    norm_rope_w<<<4096,  256, 0, stream>>>(kbb, knw, rope, 2, 256, 1024, 0);
    norm_rope_w<<<16384, 256, 0, stream>>>(qgc, qnw, rope, 4, 512, 8192, 0);

    attn_b3<<<dim3(32, 16, 2), 256, 0, stream>>>(
        qgc, kbb, vbb, ycc, QGS, KVS, YS);

    gemm256_3<float><<<dim3(16, 8, 2), 512, 0, stream>>>(
        ycc, wob, wob, wob, 16, 16, out, out, out,
        4096, YS, YS, YS, YS, 4096, 4096, 4096);
    return;
  }

  // ---- fallback tiers ----
  bool useW = true; int nb = 2, CH = 2048;
  while (CH > 256 && needT(useW, nb, CH) > ws_size) CH >>= 1;
  if (needT(useW, nb, CH) > ws_size) {
    useW = false; CH = 2048;
    while (CH > 128 && needT(useW, nb, CH) > ws_size) CH >>= 1;
    if (needT(useW, nb, CH) > ws_size) {
      nb = 1; CH = 2048;
      while (CH > 128 && needT(useW, nb, CH) > ws_size) CH >>= 1;
    }
  }
  if (needT(useW, nb, CH) > ws_size) {
    write_val<<<1, 64, 0, stream>>>(out, 3000.0f);
    return;
  }

  bf16* wqb = nullptr; bf16* wkb = nullptr; bf16* wvb = nullptr; bf16* wob = nullptr;
  if (useW) {
    wqb = (bf16*)ws;               ws += 33554432ull * 2;
    wkb = (bf16*)ws;               ws += 4194304ull * 2;
    wvb = (bf16*)ws;               ws += 4194304ull * 2;
    wob = (bf16*)ws;               ws += 16777216ull * 2;
  }
  bf16* xb  = (bf16*)ws;           ws += (size_t)nb * XS * 2;
  bf16* kbb = (bf16*)ws;           ws += (size_t)nb * KVS * 2;
  bf16* vbb = (bf16*)ws;           ws += (size_t)nb * KVS * 2;
  bf16* qgc = (bf16*)ws;           ws += (size_t)CH * 8192 * 2;
  bf16* ycc = (bf16*)ws;

  if (useW) {
    cvt_pass<<<2048, 256, 0, stream>>>(wq, wqb, 33554432 / 8);
    cvt_pass<<<512,  256, 0, stream>>>(wk, wkb, 4194304 / 8);
    cvt_pass<<<512,  256, 0, stream>>>(wv, wvb, 4194304 / 8);
    cvt_pass<<<1024, 256, 0, stream>>>(wo, wob, 16777216 / 8);
  }

  if (nb == 2) {
    cvt_pass<<<2048, 256, 0, stream>>>(x, xb, 2 * XS / 8);
    if (useW)
      gemm256_3<bf16><<<dim3(8, 8, 2), 512, 0, stream>>>(
          xb, wkb, wvb, wvb, 4, 8, kbb, vbb, vbb,
          4096, XS, KVS, KVS, KVS, 1024, 1024, 1024);
    else
      gemm_bf<bf16, float><<<dim3(16, 16, 2), 256, 0, stream>>>(
          xb, wk, wv, 8, kbb, vbb, 4096, XS, KVS);
    norm_rope_w<<<4096, 256, 0, stream>>>(kbb, knw, rope, 2, 256, 1024, 0);
  }

  for (int b = 0; b < 2; ++b) {
    const int bi = (nb == 2) ? b : 0;
    if (nb == 1) {
      cvt_pass<<<2048, 256, 0, stream>>>(x + (size_t)b * XS, xb, XS / 8);
      if (useW)
        gemm256_3<bf16><<<dim3(8, 8, 1), 512, 0, stream>>>(
            xb, wkb, wvb, wvb, 4, 8, kbb, vbb, vbb,
            4096, 0, 0, 0, 0, 1024, 1024, 1024);
      else
        gemm_bf<bf16, float><<<dim3(16, 16, 1), 256, 0, stream>>>(
            xb, wk, wv, 8, kbb, vbb, 4096, 0, 0);
      norm_rope_w<<<2048, 256, 0, stream>>>(kbb, knw, rope, 2, 256, 1024, 0);
    }
    const bf16* xbb = xb + (size_t)bi * XS;
    bf16* kbbb = kbb + (size_t)bi * KVS;
    bf16* vbbb = vbb + (size_t)bi * KVS;
    for (int c = 0; c < 2048; c += CH) {
      if (useW)
        gemm256_3<bf16><<<dim3(32, CH / 256, 1), 512, 0, stream>>>(
            xbb + (size_t)c * 4096, wqb, wqb, wqb, 32, 32, qgc, qgc, qgc,
            4096, 0, 0, 0, 0, 8192, 8192, 8192);
      else
        gemm_bf<bf16, float><<<dim3(64, CH / 128, 1), 256, 0, stream>>>(
            xbb + (size_t)c * 4096, wq, wq, 64, qgc, qgc, 4096, 0, 0);
      norm_rope_w<<<CH * 4, 256, 0, stream>>>(qgc, qnw, rope, 4, 512, 8192, c);
      attn_b3<<<dim3(CH / 64, 16, 1), 256, 0, stream>>>(
          qgc, kbbb, vbbb, ycc, 0, 0, 0);
      float* outc = out + ((size_t)b * 2048 + c) * 4096;
      if (useW)
        gemm256_3<float><<<dim3(16, CH / 256, 1), 512, 0, stream>>>(
            ycc, wob, wob, wob, 16, 16, outc, outc, outc,
            4096, 0, 0, 0, 0, 4096, 4096, 4096);
      else
        gemm_bf<float, float><<<dim3(32, CH / 128, 1), 256, 0, stream>>>(
            ycc, wo, wo, 32, outc, outc, 4096, 0, 0);
    }
  }
}

// Round 23
// 820.581 us; speedup vs baseline: 1.0268x; 1.0001x over previous
//
#include <hip/hip_runtime.h>
#include <hip/hip_bf16.h>
#include <cstdint>
#include <cstddef>

typedef __bf16 bf16;
typedef __bf16 bf16x8 __attribute__((ext_vector_type(8)));
typedef __bf16 bf16x4 __attribute__((ext_vector_type(4)));
typedef float f32x4 __attribute__((ext_vector_type(4)));

#define MFMA16(a, b, c) __builtin_amdgcn_mfma_f32_16x16x32_bf16((a), (b), (c), 0, 0, 0)
#define GLL16(gp, lp) __builtin_amdgcn_global_load_lds( \
    (const __attribute__((address_space(1))) void*)(gp), \
    (__attribute__((address_space(3))) void*)(lp), 16, 0, 0)

#define LDS_FENCE() do { \
    __builtin_amdgcn_sched_barrier(0); \
    asm volatile("s_waitcnt lgkmcnt(0)" ::: "memory"); \
    __builtin_amdgcn_sched_barrier(0); \
  } while (0)

__device__ __forceinline__ bf16x8 cvt8(const float* f) {
  bf16x8 h;
  #pragma unroll
  for (int j = 0; j < 8; ++j) h[j] = (bf16)f[j];
  return h;
}

__device__ __forceinline__ bf16x8 ldb8(const bf16* p) {
  return *(const bf16x8*)p;
}
__device__ __forceinline__ bf16x8 ldb8(const float* p) {
  float f[8];
  *(f32x4*)&f[0] = *(const f32x4*)p;
  *(f32x4*)&f[4] = *(const f32x4*)(p + 4);
  return cvt8(f);
}

__global__ void write_val(float* o, float v) {
  if (threadIdx.x == 0 && blockIdx.x == 0) o[0] = v;
}

// ---------------------------------------------------------------------------
// fp32 -> bf16 conversion pass. n8 = elems/8.
// ---------------------------------------------------------------------------
__global__ __launch_bounds__(256) void cvt_pass(
    const float* __restrict__ src, bf16* __restrict__ dst, size_t n8)
{
  for (size_t i = (size_t)blockIdx.x * 256 + threadIdx.x; i < n8;
       i += (size_t)gridDim.x * 256) {
    float f[8];
    *(f32x4*)&f[0] = *(const f32x4*)&src[i * 8];
    *(f32x4*)&f[4] = *(const f32x4*)&src[i * 8 + 4];
    *(bf16x8*)&dst[i * 8] = cvt8(f);
  }
}

// ---------------------------------------------------------------------------
// Pipelined 256x256 bf16 GEMM, THREE B/C regions. BK=32, 4 LDS buffers,
// counted vmcnt(8), 8 waves, GLL16 staging, conflict-free swizzle
// (key (row>>1)&3, verified R18: SQ_LDS_BANK_CONFLICT = 0).
// R19 schedule — the ONLY replay-stable variant (validated R19, R21):
// single barrier per tile; 12 ds_reads -> stage t+3 -> FULL lgkmcnt(0)
// drain -> 32 MFMAs. Both counted-lgkm overlap attempts (R20 hand-counted,
// R22 compiler-counted) raced under graph replay — the full drain is
// REQUIRED for cross-wave buffer-reuse safety in this structure.
// ---------------------------------------------------------------------------
template <typename CT>
__global__ __launch_bounds__(512, 2) void gemm256_3(
    const bf16* __restrict__ A,
    const bf16* __restrict__ B0, const bf16* __restrict__ B1,
    const bf16* __restrict__ B2, int n1, int n2,
    CT* __restrict__ C0, CT* __restrict__ C1, CT* __restrict__ C2,
    int K, size_t aBatch, size_t cb0, size_t cb1, size_t cb2,
    int ld0, int ld1, int ld2)
{
  __shared__ bf16 lds[4 * 16384];
  const int tid  = threadIdx.x;
  const int wave = tid >> 6, lane = tid & 63;
  const int g = lane >> 4, q = lane & 15;
  const int wm = wave >> 2, wn = wave & 3;
  const int bx = blockIdx.x, by = blockIdx.y, bz = blockIdx.z;

  const int r = (bx < n1) ? 0 : (bx < n2) ? 1 : 2;
  const bf16* Bw = (r == 0) ? B0 : (r == 1) ? B1 : B2;
  CT* C = ((r == 0) ? C0 : (r == 1) ? C1 : C2)
          + (size_t)bz * ((r == 0) ? cb0 : (r == 1) ? cb1 : cb2);
  const int bn = bx - ((r == 0) ? 0 : (r == 1) ? n1 : n2);
  const int ldc = (r == 0) ? ld0 : (r == 1) ? ld1 : ld2;
  const size_t n0 = (size_t)bn * 256;
  const size_t m0 = (size_t)by * 256;
  const bf16* Ap = A + (size_t)bz * aBatch;

  // staging: dest granule tid -> row = i*128 + (tid>>2), slot = tid&3;
  // source slot pre-swizzled by key (row>>1)&3 = (tid>>3)&3.
  const int srow = tid >> 2;
  const int scol = (((tid & 3) ^ ((tid >> 3) & 3)) << 3);
  const int NT = K >> 5;

  f32x4 acc[8][4] = {};

  auto STAGE_A = [&](int t) {
    const int k0 = t << 5;
    char* base = (char*)lds + (size_t)(t & 3) * 32768 + wave * 1024;
    #pragma unroll
    for (int i = 0; i < 2; ++i)
      GLL16(&Ap[(m0 + i * 128 + srow) * (size_t)K + k0 + scol],
            base + i * 8192);
  };
  auto STAGE_B = [&](int t) {
    const int k0 = t << 5;
    char* base = (char*)lds + (size_t)(t & 3) * 32768 + 16384 + wave * 1024;
    #pragma unroll
    for (int i = 0; i < 2; ++i)
      GLL16(&Bw[(n0 + i * 128 + srow) * (size_t)K + k0 + scol],
            base + i * 8192);
  };

  STAGE_A(0); STAGE_B(0);
  STAGE_A(1); STAGE_B(1);
  STAGE_A(2); STAGE_B(2);

  const int rsl = ((g ^ ((q >> 1) & 3)) << 3);   // read slot, key (row>>1)&3

  for (int t = 0; t < NT; ++t) {
    asm volatile("s_waitcnt vmcnt(8)" ::: "memory");
    __builtin_amdgcn_sched_barrier(0);
    __builtin_amdgcn_s_barrier();
    const bf16* lA = lds + (size_t)(t & 3) * 16384;
    const bf16* lB = lA + 8192;

    bf16x8 bfr[4], af[8];
    #pragma unroll
    for (int fn = 0; fn < 4; ++fn)
      bfr[fn] = *(const bf16x8*)&lB[(wn * 64 + fn * 16 + q) * 32 + rsl];
    #pragma unroll
    for (int fm = 0; fm < 8; ++fm)
      af[fm] = *(const bf16x8*)&lA[(wm * 128 + fm * 16 + q) * 32 + rsl];
    if (t + 3 < NT) { STAGE_A(t + 3); STAGE_B(t + 3); }
    asm volatile("s_waitcnt lgkmcnt(0)" ::: "memory");
    __builtin_amdgcn_sched_barrier(0);
    __builtin_amdgcn_s_setprio(1);
    #pragma unroll
    for (int fm = 0; fm < 8; ++fm)
      #pragma unroll
      for (int fn = 0; fn < 4; ++fn)
        acc[fm][fn] = MFMA16(af[fm], bfr[fn], acc[fm][fn]);
    __builtin_amdgcn_s_setprio(0);
  }

  #pragma unroll
  for (int fm = 0; fm < 8; ++fm)
    #pragma unroll
    for (int fn = 0; fn < 4; ++fn)
      #pragma unroll
      for (int rr = 0; rr < 4; ++rr) {
        const size_t row = m0 + wm * 128 + fm * 16 + g * 4 + rr;
        C[row * (size_t)ldc + n0 + wn * 64 + fn * 16 + q] = (CT)acc[fm][fn][rr];
      }
}

// ---------------------------------------------------------------------------
// 128^2 reg-staged GEMM (fp32-B fallback tier only).
// ---------------------------------------------------------------------------
template <typename CT, typename BT>
__global__ __launch_bounds__(256) void gemm_bf(
    const bf16* __restrict__ A,
    const BT* __restrict__ B0, const BT* __restrict__ B1, int nsplit,
    CT* __restrict__ C0, CT* __restrict__ C1,
    int K, size_t aBatch, size_t cBatch)
{
  constexpr int LDST = 72;
  __shared__ bf16 lA[128 * LDST];
  __shared__ bf16 lB[128 * LDST];
  const int tid  = threadIdx.x;
  const int wave = tid >> 6;
  const int lane = tid & 63;
  const int g = lane >> 4, q = lane & 15;
  const bool r0 = (int)blockIdx.x < nsplit;
  const BT* Bw = r0 ? B0 : B1;
  CT* C = (r0 ? C0 : C1) + blockIdx.z * cBatch;
  const int bn = r0 ? blockIdx.x : blockIdx.x - nsplit;
  const int ldc = (r0 ? nsplit : ((int)gridDim.x - nsplit)) * 128;
  const size_t n0 = (size_t)bn * 128;
  const size_t m0 = (size_t)blockIdx.y * 128;
  const bf16* Ap = A + blockIdx.z * aBatch;
  const int wm = wave >> 1, wn = wave & 1;
  const int sr = tid >> 3, sc8 = (tid & 7) << 3;

  f32x4 acc[4][4] = {};

  for (int k0 = 0; k0 < K; k0 += 64) {
    __syncthreads();
    #pragma unroll
    for (int i = 0; i < 4; ++i) {
      const int row = i * 32 + sr;
      *(bf16x8*)&lA[row * LDST + sc8] = ldb8(&Ap[(m0 + row) * (size_t)K + k0 + sc8]);
      *(bf16x8*)&lB[row * LDST + sc8] = ldb8(&Bw[(n0 + row) * (size_t)K + k0 + sc8]);
    }
    __syncthreads();
    #pragma unroll
    for (int kk = 0; kk < 2; ++kk) {
      bf16x8 af[4], bfr[4];
      #pragma unroll
      for (int f = 0; f < 4; ++f) {
        af[f]  = *(const bf16x8*)&lA[(wm * 64 + f * 16 + q) * LDST + kk * 32 + g * 8];
        bfr[f] = *(const bf16x8*)&lB[(wn * 64 + f * 16 + q) * LDST + kk * 32 + g * 8];
      }
      #pragma unroll
      for (int fm = 0; fm < 4; ++fm)
        #pragma unroll
        for (int fn = 0; fn < 4; ++fn)
          acc[fm][fn] = MFMA16(af[fm], bfr[fn], acc[fm][fn]);
    }
  }

  #pragma unroll
  for (int fm = 0; fm < 4; ++fm)
    #pragma unroll
    for (int fn = 0; fn < 4; ++fn)
      #pragma unroll
      for (int r = 0; r < 4; ++r) {
        const size_t row = m0 + wm * 64 + fm * 16 + g * 4 + r;
        C[row * (size_t)ldc + n0 + wn * 64 + fn * 16 + q] = (CT)acc[fm][fn][r];
      }
}

// ---------------------------------------------------------------------------
// Gemma RMSNorm + RoPE, wave per (row, head): 64 lanes x 4 elems, in place.
// ---------------------------------------------------------------------------
__global__ __launch_bounds__(256) void norm_rope_w(
    bf16* __restrict__ data, const float* __restrict__ w,
    const float* __restrict__ ropec, int lnh, int hstride, int rowlen,
    int s_off)
{
  const int lane = threadIdx.x & 63;
  const int wid  = blockIdx.x * 4 + (threadIdx.x >> 6);
  const int m = wid >> lnh;
  const int h = wid & ((1 << lnh) - 1);
  const int s = (s_off + m) & 2047;

  bf16* p = data + (size_t)m * rowlen + h * hstride + lane * 4;
  const bf16x4 xv = *(const bf16x4*)p;
  float x0 = (float)xv[0], x1 = (float)xv[1], x2 = (float)xv[2], x3 = (float)xv[3];
  float ss = x0*x0 + x1*x1 + x2*x2 + x3*x3;
  #pragma unroll
  for (int d = 1; d < 64; d <<= 1) ss += __shfl_xor(ss, d, 64);
  const float rr = rsqrtf(ss * (1.0f / 256.0f) + 1e-6f);
  const f32x4 wv4 = *(const f32x4*)&w[lane * 4];
  x0 *= rr * (1.0f + wv4[0]);
  x1 *= rr * (1.0f + wv4[1]);
  x2 *= rr * (1.0f + wv4[2]);
  x3 *= rr * (1.0f + wv4[3]);

  const float o0 = __shfl_xor(x0, 8, 64);
  const float o1 = __shfl_xor(x1, 8, 64);
  const float o2 = __shfl_xor(x2, 8, 64);
  const float o3 = __shfl_xor(x3, 8, 64);
  if (lane < 16) {
    const int c0 = lane * 4;
    const float* rc = ropec + (size_t)s * 128;
    const float sgn = (lane < 8) ? -1.0f : 1.0f;
    x0 = x0 * rc[c0]     + sgn * o0 * rc[64 + c0];
    x1 = x1 * rc[c0 + 1] + sgn * o1 * rc[64 + c0 + 1];
    x2 = x2 * rc[c0 + 2] + sgn * o2 * rc[64 + c0 + 2];
    x3 = x3 * rc[c0 + 3] + sgn * o3 * rc[64 + c0 + 3];
  }
  bf16x4 ov; ov[0] = (bf16)x0; ov[1] = (bf16)x1; ov[2] = (bf16)x2; ov[3] = (bf16)x3;
  *(bf16x4*)p = ov;
}

// ---------------------------------------------------------------------------
// bf16 MFMA flash attention v3 (R17-verified): double-buffered K (GLL) and
// V^T; per-tile prefetch; defer-max; setprio. 4 waves x 16 Q.
// ---------------------------------------------------------------------------
__global__ __launch_bounds__(256) void attn_b3(
    const bf16* __restrict__ qg, const bf16* __restrict__ kb,
    const bf16* __restrict__ vb, bf16* __restrict__ yb,
    size_t qgBatch, size_t kvBatch, size_t yBatch)
{
  __shared__ bf16 lK[2][32 * 256];
  __shared__ bf16 lVt[2][256 * 40];
  __shared__ bf16 lP[4 * 16 * 40];
  const int tid  = threadIdx.x;
  const int wave = tid >> 6, lane = tid & 63;
  const int g = lane >> 4, qc = lane & 15;
  const int h = blockIdx.y, q0 = blockIdx.x * 64, kvh = h >> 2;
  const int z = blockIdx.z;
  const bf16* qgp = qg + z * qgBatch;
  const bf16* kbase = kb + z * kvBatch + kvh * 256;
  const bf16* vbase = vb + z * kvBatch + kvh * 256;
  const int qrow = q0 + wave * 16 + qc;

  bf16x8 qf[8];
  {
    const bf16* qp = qgp + (size_t)qrow * 8192 + h * 512;
    #pragma unroll
    for (int kq = 0; kq < 8; ++kq)
      qf[kq] = *(const bf16x8*)&qp[kq * 32 + g * 8];
  }

  f32x4 o[16] = {};
  float mrow = -1e30f, lrow = 0.0f;
  const float scale = 0.0625f;
  const float L2E = 1.44269504f;
  const int vp = (tid & 15) * 2, vc = (tid >> 4) * 16;
  bf16* const pl = lP + wave * (16 * 40);
  const int krw = wave * 2 + (lane >> 5);
  const int ksl = lane & 31;

  auto stageK = [&](int tile, int buf) {
    const int t0 = tile * 32;
    #pragma unroll
    for (int i = 0; i < 4; ++i) {
      const int row = i * 8 + krw;
      GLL16(&kbase[(size_t)(t0 + row) * 1024 + ((ksl ^ (row & 7)) << 3)],
            (char*)lK[buf] + i * 4096 + wave * 1024);
    }
  };
  auto loadV = [&](int tile, bf16x8& a0, bf16x8& b0, bf16x8& a1, bf16x8& b1) {
    const bf16* p0 = vbase + (size_t)(tile * 32 + vp) * 1024 + vc;
    a0 = *(const bf16x8*)(p0);
    b0 = *(const bf16x8*)(p0 + 8);
    a1 = *(const bf16x8*)(p0 + 1024);
    b1 = *(const bf16x8*)(p0 + 1032);
  };
  auto writeVt = [&](int buf, const bf16x8& a0, const bf16x8& b0,
                     const bf16x8& a1, const bf16x8& b1) {
    unsigned* dst = (unsigned*)lVt[buf];
    #pragma unroll
    for (int j = 0; j < 8; ++j) {
      const int o0 = (vc + j) * 20 + (vp >> 1);
      const int o1 = (vc + 8 + j) * 20 + (vp >> 1);
      dst[o0] = (unsigned)__builtin_bit_cast(unsigned short, (bf16)a0[j]) |
                ((unsigned)__builtin_bit_cast(unsigned short, (bf16)a1[j]) << 16);
      dst[o1] = (unsigned)__builtin_bit_cast(unsigned short, (bf16)b0[j]) |
                ((unsigned)__builtin_bit_cast(unsigned short, (bf16)b1[j]) << 16);
    }
  };

  {
    bf16x8 a0, b0, a1, b1;
    stageK(0, 0);
    loadV(0, a0, b0, a1, b1);
    asm volatile("s_waitcnt vmcnt(0)" ::: "memory");
    __builtin_amdgcn_sched_barrier(0);
    writeVt(0, a0, b0, a1, b1);
  }

  const int NT = 64;
  for (int tile = 0; tile < NT; ++tile) {
    __syncthreads();
    const int cur = tile & 1;

    bf16x8 a0, b0, a1, b1;
    const bool pf = (tile + 1 < NT);
    if (pf) {
      stageK(tile + 1, cur ^ 1);
      loadV(tile + 1, a0, b0, a1, b1);
    }

    f32x4 st[2];
    #pragma unroll
    for (int half = 0; half < 2; ++half) {
      f32x4 s = {0.f, 0.f, 0.f, 0.f};
      __builtin_amdgcn_s_setprio(1);
      #pragma unroll
      for (int kq = 0; kq < 8; ++kq) {
        const bf16x8 ka = *(const bf16x8*)
            &lK[cur][(half * 16 + qc) * 256 + (((kq * 4 + g) ^ (qc & 7)) << 3)];
        s = MFMA16(ka, qf[kq], s);
      }
      __builtin_amdgcn_s_setprio(0);
      st[half] = s;
    }

    float pm = st[0][0];
    #pragma unroll
    for (int r = 1; r < 4; ++r) pm = fmaxf(pm, st[0][r]);
    #pragma unroll
    for (int r = 0; r < 4; ++r) pm = fmaxf(pm, st[1][r]);
    pm *= scale;
    pm = fmaxf(pm, __shfl_xor(pm, 16, 64));
    pm = fmaxf(pm, __shfl_xor(pm, 32, 64));

    if (!__all(pm <= mrow + 8.0f)) {
      const float mnew = fmaxf(mrow, pm);
      const float corr = exp2f((mrow - mnew) * L2E);
      lrow *= corr;
      #pragma unroll
      for (int f = 0; f < 16; ++f) {
        o[f][0] *= corr; o[f][1] *= corr; o[f][2] *= corr; o[f][3] *= corr;
      }
      mrow = mnew;
    }

    float ladd = 0.0f;
    #pragma unroll
    for (int half = 0; half < 2; ++half) {
      bf16x4 pk;
      #pragma unroll
      for (int r = 0; r < 4; ++r) {
        const float pv = exp2f((st[half][r] * scale - mrow) * L2E);
        ladd += pv;
        pk[r] = (bf16)pv;
      }
      *(bf16x4*)&pl[qc * 40 + half * 16 + g * 4] = pk;
    }
    ladd += __shfl_xor(ladd, 16, 64);
    ladd += __shfl_xor(ladd, 32, 64);
    lrow += ladd;

    LDS_FENCE();

    const bf16x8 pb = *(const bf16x8*)&pl[qc * 40 + g * 8];
    __builtin_amdgcn_s_setprio(1);
    #pragma unroll
    for (int fm = 0; fm < 16; ++fm) {
      const bf16x8 va = *(const bf16x8*)&lVt[cur][(fm * 16 + qc) * 40 + g * 8];
      o[fm] = MFMA16(va, pb, o[fm]);
    }
    __builtin_amdgcn_s_setprio(0);

    if (pf) {
      asm volatile("s_waitcnt vmcnt(0)" ::: "memory");
      __builtin_amdgcn_sched_barrier(0);
      writeVt(cur ^ 1, a0, b0, a1, b1);
    }
  }

  const float inv = 1.0f / lrow;
  const bf16* gp = qgp + (size_t)qrow * 8192 + h * 512 + 256;
  bf16* yp = yb + z * yBatch + (size_t)qrow * 4096 + h * 256;
  #pragma unroll
  for (int fm = 0; fm < 16; ++fm) {
    const int d0 = fm * 16 + g * 4;
    bf16x4 ov;
    #pragma unroll
    for (int r = 0; r < 4; ++r) {
      const float gv = (float)gp[d0 + r];
      const float sig = 1.0f / (1.0f + exp2f(-gv * L2E));
      ov[r] = (bf16)(o[fm][r] * inv * sig);
    }
    *(bf16x4*)&yp[d0] = ov;
  }
}

// ---------------------------------------------------------------------------
extern "C" void kernel_launch(void* const* d_in, const int* in_sizes, int n_in,
                              void* d_out, int out_size, void* d_ws, size_t ws_size,
                              hipStream_t stream) {
  const float* x    = (const float*)d_in[0];
  const float* rope = (const float*)d_in[1];
  const float* wq   = (const float*)d_in[2];
  const float* wk   = (const float*)d_in[3];
  const float* wv   = (const float*)d_in[4];
  const float* wo   = (const float*)d_in[5];
  const float* qnw  = (const float*)d_in[6];
  const float* knw  = (const float*)d_in[7];
  float* out = (float*)d_out;

  if (out_size != 16777216) { write_val<<<1, 64, 0, stream>>>(out, 2000.0f); return; }
  const bool sizes_ok = (n_in == 8) &&
      in_sizes[0] == 16777216 && in_sizes[1] == 262144 &&
      in_sizes[2] == 33554432 && in_sizes[3] == 4194304 &&
      in_sizes[4] == 4194304  && in_sizes[5] == 16777216 &&
      in_sizes[6] == 256      && in_sizes[7] == 256;
  if (!sizes_ok) { write_val<<<1, 64, 0, stream>>>(out, 2500.0f); return; }

  const size_t XS  = 2048ull * 4096;
  const size_t KVS = 2048ull * 1024;
  const size_t QGS = 2048ull * 8192;
  const size_t YS  = 2048ull * 4096;
  const size_t WFIX = (33554432ull + 4194304 + 4194304 + 16777216) * 2;

  const size_t needFull = WFIX + 2 * XS * 2 + 4 * KVS * 2 + 2 * QGS * 2 + 2 * YS * 2;
  auto needT = [&](bool w, int nb, int CHv) -> size_t {
    return (w ? WFIX : 0) + (size_t)nb * XS * 2 + (size_t)nb * KVS * 4
         + (size_t)CHv * 8192 * 2 + (size_t)CHv * 4096 * 2;
  };

  char* ws = (char*)d_ws;

  if (needFull <= ws_size) {
    bf16* wqb = (bf16*)ws;           ws += 33554432ull * 2;
    bf16* wkb = (bf16*)ws;           ws += 4194304ull * 2;
    bf16* wvb = (bf16*)ws;           ws += 4194304ull * 2;
    bf16* wob = (bf16*)ws;           ws += 16777216ull * 2;
    bf16* xb  = (bf16*)ws;           ws += 2 * XS * 2;
    bf16* kbb = (bf16*)ws;           ws += 2 * KVS * 2;
    bf16* vbb = (bf16*)ws;           ws += 2 * KVS * 2;
    bf16* qgc = (bf16*)ws;           ws += 2 * QGS * 2;
    bf16* ycc = (bf16*)ws;

    cvt_pass<<<2048, 256, 0, stream>>>(wq, wqb, 33554432 / 8);
    cvt_pass<<<512,  256, 0, stream>>>(wk, wkb, 4194304 / 8);
    cvt_pass<<<512,  256, 0, stream>>>(wv, wvb, 4194304 / 8);
    cvt_pass<<<1024, 256, 0, stream>>>(wo, wob, 16777216 / 8);
    cvt_pass<<<2048, 256, 0, stream>>>(x, xb, 2 * XS / 8);

    gemm256_3<bf16><<<dim3(40, 8, 2), 512, 0, stream>>>(
        xb, wkb, wvb, wqb, 4, 8, kbb, vbb, qgc,
        4096, XS, KVS, KVS, QGS, 1024, 1024, 8192);

    norm_rope_w<<<4096,  256, 0, stream>>>(kbb, knw, rope, 2, 256, 1024, 0);
    norm_rope_w<<<16384, 256, 0, stream>>>(qgc, qnw, rope, 4, 512, 8192, 0);

    attn_b3<<<dim3(32, 16, 2), 256, 0, stream>>>(
        qgc, kbb, vbb, ycc, QGS, KVS, YS);

    gemm256_3<float><<<dim3(16, 8, 2), 512, 0, stream>>>(
        ycc, wob, wob, wob, 16, 16, out, out, out,
        4096, YS, YS, YS, YS, 4096, 4096, 4096);
    return;
  }

  // ---- fallback tiers ----
  bool useW = true; int nb = 2, CH = 2048;
  while (CH > 256 && needT(useW, nb, CH) > ws_size) CH >>= 1;
  if (needT(useW, nb, CH) > ws_size) {
    useW = false; CH = 2048;
    while (CH > 128 && needT(useW, nb, CH) > ws_size) CH >>= 1;
    if (needT(useW, nb, CH) > ws_size) {
      nb = 1; CH = 2048;
      while (CH > 128 && needT(useW, nb, CH) > ws_size) CH >>= 1;
    }
  }
  if (needT(useW, nb, CH) > ws_size) {
    write_val<<<1, 64, 0, stream>>>(out, 3000.0f);
    return;
  }

  bf16* wqb = nullptr; bf16* wkb = nullptr; bf16* wvb = nullptr; bf16* wob = nullptr;
  if (useW) {
    wqb = (bf16*)ws;               ws += 33554432ull * 2;
    wkb = (bf16*)ws;               ws += 4194304ull * 2;
    wvb = (bf16*)ws;               ws += 4194304ull * 2;
    wob = (bf16*)ws;               ws += 16777216ull * 2;
  }
  bf16* xb  = (bf16*)ws;           ws += (size_t)nb * XS * 2;
  bf16* kbb = (bf16*)ws;           ws += (size_t)nb * KVS * 2;
  bf16* vbb = (bf16*)ws;           ws += (size_t)nb * KVS * 2;
  bf16* qgc = (bf16*)ws;           ws += (size_t)CH * 8192 * 2;
  bf16* ycc = (bf16*)ws;

  if (useW) {
    cvt_pass<<<2048, 256, 0, stream>>>(wq, wqb, 33554432 / 8);
    cvt_pass<<<512,  256, 0, stream>>>(wk, wkb, 4194304 / 8);
    cvt_pass<<<512,  256, 0, stream>>>(wv, wvb, 4194304 / 8);
    cvt_pass<<<1024, 256, 0, stream>>>(wo, wob, 16777216 / 8);
  }

  if (nb == 2) {
    cvt_pass<<<2048, 256, 0, stream>>>(x, xb, 2 * XS / 8);
    if (useW)
      gemm256_3<bf16><<<dim3(8, 8, 2), 512, 0, stream>>>(
          xb, wkb, wvb, wvb, 4, 8, kbb, vbb, vbb,
          4096, XS, KVS, KVS, KVS, 1024, 1024, 1024);
    else
      gemm_bf<bf16, float><<<dim3(16, 16, 2), 256, 0, stream>>>(
          xb, wk, wv, 8, kbb, vbb, 4096, XS, KVS);
    norm_rope_w<<<4096, 256, 0, stream>>>(kbb, knw, rope, 2, 256, 1024, 0);
  }

  for (int b = 0; b < 2; ++b) {
    const int bi = (nb == 2) ? b : 0;
    if (nb == 1) {
      cvt_pass<<<2048, 256, 0, stream>>>(x + (size_t)b * XS, xb, XS / 8);
      if (useW)
        gemm256_3<bf16><<<dim3(8, 8, 1), 512, 0, stream>>>(
            xb, wkb, wvb, wvb, 4, 8, kbb, vbb, vbb,
            4096, 0, 0, 0, 0, 1024, 1024, 1024);
      else
        gemm_bf<bf16, float><<<dim3(16, 16, 1), 256, 0, stream>>>(
            xb, wk, wv, 8, kbb, vbb, 4096, 0, 0);
      norm_rope_w<<<2048, 256, 0, stream>>>(kbb, knw, rope, 2, 256, 1024, 0);
    }
    const bf16* xbb = xb + (size_t)bi * XS;
    bf16* kbbb = kbb + (size_t)bi * KVS;
    bf16* vbbb = vbb + (size_t)bi * KVS;
    for (int c = 0; c < 2048; c += CH) {
      if (useW)
        gemm256_3<bf16><<<dim3(32, CH / 256, 1), 512, 0, stream>>>(
            xbb + (size_t)c * 4096, wqb, wqb, wqb, 32, 32, qgc, qgc, qgc,
            4096, 0, 0, 0, 0, 8192, 8192, 8192);
      else
        gemm_bf<bf16, float><<<dim3(64, CH / 128, 1), 256, 0, stream>>>(
            xbb + (size_t)c * 4096, wq, wq, 64, qgc, qgc, 4096, 0, 0);
      norm_rope_w<<<CH * 4, 256, 0, stream>>>(qgc, qnw, rope, 4, 512, 8192, c);
      attn_b3<<<dim3(CH / 64, 16, 1), 256, 0, stream>>>(
          qgc, kbbb, vbbb, ycc, 0, 0, 0);
      float* outc = out + ((size_t)b * 2048 + c) * 4096;
      if (useW)
        gemm256_3<float><<<dim3(16, CH / 256, 1), 512, 0, stream>>>(
            ycc, wob, wob, wob, 16, 16, outc, outc, outc,
            4096, 0, 0, 0, 0, 4096, 4096, 4096);
      else
        gemm_bf<float, float><<<dim3(32, CH / 128, 1), 256, 0, stream>>>(
            ycc, wo, wo, 32, outc, outc, 4096, 0, 0);
    }
  }
}